// Round 1
// 865.471 us; speedup vs baseline: 1.0731x; 1.0731x over previous
//
#include <hip/hip_runtime.h>
#include <stdint.h>

#define L 2048
#define DMODEL 2048
#define NH 16

typedef __bf16 bf16x8 __attribute__((ext_vector_type(8)));
typedef float f32x4 __attribute__((ext_vector_type(4)));
typedef short s16x4 __attribute__((ext_vector_type(4)));

__device__ __forceinline__ unsigned short f2bf(float f) {
    union { float f; unsigned int i; } w; w.f = f;
    unsigned int u = w.i;
    unsigned int r = u + 0x7fffu + ((u >> 16) & 1u);
    return (unsigned short)(r >> 16);
}

// ---------------------------------------------------------------------------
// Tiled bf16-MFMA GEMM, C = alpha * A (MxK) * B'(NxK)^T.  B' is B transposed
// (row n of B' holds column n of B, contiguous in K), always bf16.
// AF32=1: A is fp32 in memory, converted to bf16 (RNE) during LDS staging.
// CMODE 0: C bf16 row-major [m][n]   (ldc = row stride)
// CMODE 1: C bf16 transposed [n][m]  (ldc = row stride of transposed mat)
// CMODE 2: C fp32 row-major [m][n]
// Grid (N/128, M/128, batch), block 256 (4 waves).  lda/ldb/ldc/sA/sB/sC in
// ELEMENTS of the respective dtype.
// ---------------------------------------------------------------------------
template<int CMODE, int AF32>
__global__ __launch_bounds__(256, 2)
void gemm_bt(const void* __restrict__ Av,
             const unsigned short* __restrict__ B,
             void* __restrict__ C,
             int M, int N, int K, int lda, int ldb, int ldc,
             long long sA, long long sB, long long sC, float alpha)
{
    __shared__ unsigned short As[128 * 32];
    __shared__ unsigned short Bs[128 * 32];

    const int tid  = threadIdx.x;
    const int wave = tid >> 6;
    const int lane = tid & 63;
    const int quad = lane >> 4;
    const int l16  = lane & 15;

    const int tileN = blockIdx.x * 128;
    const int tileM = blockIdx.y * 128;

    const unsigned short* A16 = (const unsigned short*)Av + (AF32 ? 0 : (long long)blockIdx.z * sA);
    const float*          A32 = (const float*)Av          + (AF32 ? (long long)blockIdx.z * sA : 0);
    B += (long long)blockIdx.z * sB;

    const int wm = (wave >> 1) * 64;
    const int wn = (wave & 1) * 64;

    // 512 16B chunks cover a 128x32 bf16 tile; thread stages chunks tid, tid+256.
    // chunk ch -> row = ch>>2, k-offset = (ch&3)*8; LDS elem offset = ch*8.
    const int ch0 = tid, ch1 = tid + 256;
    const int r0a = ch0 >> 2, kc0 = (ch0 & 3) * 8;
    const int r1a = ch1 >> 2, kc1 = (ch1 & 3) * 8;

    f32x4 acc[4][4] = {};

    for (int k0 = 0; k0 < K; k0 += 32) {
        int4 a0, a1;
        if (AF32) {
            const float* p0 = A32 + (long long)(tileM + r0a) * lda + (k0 + kc0);
            const float* p1 = A32 + (long long)(tileM + r1a) * lda + (k0 + kc1);
            const float4 f00 = *(const float4*)p0;
            const float4 f01 = *(const float4*)(p0 + 4);
            const float4 f10 = *(const float4*)p1;
            const float4 f11 = *(const float4*)(p1 + 4);
            union { int4 v; unsigned short u[8]; } t0, t1;
            t0.u[0] = f2bf(f00.x); t0.u[1] = f2bf(f00.y); t0.u[2] = f2bf(f00.z); t0.u[3] = f2bf(f00.w);
            t0.u[4] = f2bf(f01.x); t0.u[5] = f2bf(f01.y); t0.u[6] = f2bf(f01.z); t0.u[7] = f2bf(f01.w);
            t1.u[0] = f2bf(f10.x); t1.u[1] = f2bf(f10.y); t1.u[2] = f2bf(f10.z); t1.u[3] = f2bf(f10.w);
            t1.u[4] = f2bf(f11.x); t1.u[5] = f2bf(f11.y); t1.u[6] = f2bf(f11.z); t1.u[7] = f2bf(f11.w);
            a0 = t0.v; a1 = t1.v;
        } else {
            a0 = *(const int4*)(A16 + (long long)(tileM + r0a) * lda + (k0 + kc0));
            a1 = *(const int4*)(A16 + (long long)(tileM + r1a) * lda + (k0 + kc1));
        }
        const int4 b0 = *(const int4*)(B + (long long)(tileN + r0a) * ldb + (k0 + kc0));
        const int4 b1 = *(const int4*)(B + (long long)(tileN + r1a) * ldb + (k0 + kc1));

        __syncthreads();             // previous iteration's LDS reads complete
        *(int4*)(As + ch0 * 8) = a0;
        *(int4*)(As + ch1 * 8) = a1;
        *(int4*)(Bs + ch0 * 8) = b0;
        *(int4*)(Bs + ch1 * 8) = b1;
        __syncthreads();             // staging visible

        bf16x8 af[4], bfr[4];
        #pragma unroll
        for (int i = 0; i < 4; ++i)
            af[i] = *(const bf16x8*)(As + (wm + i * 16 + l16) * 32 + quad * 8);
        #pragma unroll
        for (int i = 0; i < 4; ++i)
            bfr[i] = *(const bf16x8*)(Bs + (wn + i * 16 + l16) * 32 + quad * 8);
        #pragma unroll
        for (int i = 0; i < 4; ++i)
            #pragma unroll
            for (int j = 0; j < 4; ++j)
                acc[i][j] = __builtin_amdgcn_mfma_f32_16x16x32_bf16(af[i], bfr[j], acc[i][j], 0, 0, 0);
    }

    // Epilogue.  D layout: col = lane&15, row = quad*4 + reg   [m89-verified]
    const long long cb = (long long)blockIdx.z * sC;
    #pragma unroll
    for (int i = 0; i < 4; ++i) {
        const int r0 = tileM + wm + i * 16 + quad * 4;
        #pragma unroll
        for (int j = 0; j < 4; ++j) {
            const int c = tileN + wn + j * 16 + l16;
            f32x4 d = acc[i][j];
            if (CMODE == 0) {
                unsigned short* Cp = (unsigned short*)C + cb;
                #pragma unroll
                for (int r = 0; r < 4; ++r)
                    Cp[(long long)(r0 + r) * ldc + c] = f2bf(d[r] * alpha);
            } else if (CMODE == 1) {
                unsigned short* Cp = (unsigned short*)C + cb + (long long)c * ldc + r0;
                s16x4 pk;
                #pragma unroll
                for (int r = 0; r < 4; ++r) pk[r] = (short)f2bf(d[r] * alpha);
                *(s16x4*)Cp = pk;
            } else {
                float* Cp = (float*)C + cb;
                #pragma unroll
                for (int r = 0; r < 4; ++r)
                    Cp[(long long)(r0 + r) * ldc + c] = d[r] * alpha;
            }
        }
    }
}

// ---------------------------------------------------------------------------
// 32x32 tile transpose, fp32 in -> bf16 out. Block (32,8).
// Grid (cols/32, rows/32, batch).  out[c][r] = bf16(in[r][c])
// ---------------------------------------------------------------------------
__global__ __launch_bounds__(256)
void transpose_f2b(const float* __restrict__ in, unsigned short* __restrict__ out,
                   int rows, int cols)
{
    __shared__ float t[32][33];
    const long long base = (long long)blockIdx.z * rows * cols;
    const int c0 = blockIdx.x * 32, r0 = blockIdx.y * 32;
    const int tx = threadIdx.x, ty0 = threadIdx.y;
    #pragma unroll
    for (int jj = 0; jj < 4; ++jj) {
        const int j = ty0 + jj * 8;
        t[j][tx] = in[base + (long long)(r0 + j) * cols + (c0 + tx)];
    }
    __syncthreads();
    #pragma unroll
    for (int jj = 0; jj < 4; ++jj) {
        const int j = ty0 + jj * 8;
        out[base + (long long)(c0 + j) * rows + (r0 + tx)] = f2bf(t[tx][j]);
    }
}

// ---------------------------------------------------------------------------
// Softmax over the QUERY axis (rows) of each head's row-major (Lq x Lk) fp32
// logits, in place.  Block (64 cols, 16 row-slices) = 1024 thr.
// Grid (Lk/64, NH) = (32, 16) = 512 blocks -> 2 blocks/CU on ALL 256 CUs
// (previous (8,16)=128-block grid left half the machine idle: 15% occupancy,
//  2.45 TB/s).  Coalescing unchanged: each wave reads 64 consecutive floats.
// ---------------------------------------------------------------------------
__global__ __launch_bounds__(1024)
void col_softmax(float* __restrict__ S)
{
    __shared__ float shm[16][64], shl[16][64];
    const int tx = threadIdx.x, ty = threadIdx.y;
    const int c = blockIdx.x * 64 + tx;
    float* P = S + (long long)blockIdx.y * L * L + c;
    const int r0 = ty * (L / 16), r1 = r0 + (L / 16);

    float mmax = -1e30f, ssum = 0.f;
    for (int r = r0; r < r1; ++r) {
        float s = P[(long long)r * L];
        float mn = fmaxf(mmax, s);
        ssum = ssum * __expf(mmax - mn) + __expf(s - mn);
        mmax = mn;
    }
    shm[ty][tx] = mmax; shl[ty][tx] = ssum;
    __syncthreads();
    float M = -1e30f;
    #pragma unroll
    for (int t = 0; t < 16; ++t) M = fmaxf(M, shm[t][tx]);
    float Ls = 0.f;
    #pragma unroll
    for (int t = 0; t < 16; ++t) Ls += shl[t][tx] * __expf(shm[t][tx] - M);
    const float inv = 1.0f / Ls;
    for (int r = r0; r < r1; ++r) {
        float* p = P + (long long)r * L;
        *p = __expf(*p - M) * inv;
    }
}

// ---------------------------------------------------------------------------
// Residual + bias + LayerNorm (all fp32), one block (256 thr) per row of 2048.
// ---------------------------------------------------------------------------
__global__ __launch_bounds__(256)
void ln_resid(const float* __restrict__ ypre, const float* __restrict__ resid,
              const float* __restrict__ pb, const float* __restrict__ g,
              const float* __restrict__ bta, float* __restrict__ y)
{
    __shared__ float as_[4], as2_[4];
    const int l = blockIdx.x;
    const int tid = threadIdx.x;
    float v[8]; float s = 0.f, s2 = 0.f;
    #pragma unroll
    for (int i = 0; i < 8; ++i) {
        const int d = tid + i * 256;
        float t = ypre[(long long)l * DMODEL + d] + pb[d] + resid[(long long)l * DMODEL + d];
        v[i] = t; s += t; s2 += t * t;
    }
    #pragma unroll
    for (int off = 32; off > 0; off >>= 1) {
        s  += __shfl_down(s, off, 64);
        s2 += __shfl_down(s2, off, 64);
    }
    const int wave = tid >> 6, lane = tid & 63;
    if (lane == 0) { as_[wave] = s; as2_[wave] = s2; }
    __syncthreads();
    const float S  = as_[0] + as_[1] + as_[2] + as_[3];
    const float S2 = as2_[0] + as2_[1] + as2_[2] + as2_[3];
    const float mu  = S * (1.0f / DMODEL);
    const float var = S2 * (1.0f / DMODEL) - mu * mu;
    const float rs  = rsqrtf(var + 1e-5f);
    #pragma unroll
    for (int i = 0; i < 8; ++i) {
        const int d = tid + i * 256;
        y[(long long)l * DMODEL + d] = (v[i] - mu) * rs * g[d] + bta[d];
    }
}

// ---------------------------------------------------------------------------
extern "C" void kernel_launch(void* const* d_in, const int* in_sizes, int n_in,
                              void* d_out, int out_size, void* d_ws, size_t ws_size,
                              hipStream_t stream)
{
    const float* q  = (const float*)d_in[0];
    const float* k  = (const float*)d_in[1];
    const float* v  = (const float*)d_in[2];
    const float* Wq = (const float*)d_in[3];
    const float* Wk = (const float*)d_in[4];
    const float* Wv = (const float*)d_in[5];
    const float* Pw = (const float*)d_in[6];
    const float* Pb = (const float*)d_in[7];
    const float* Lg = (const float*)d_in[8];
    const float* Lb = (const float*)d_in[9];

    float* y    = (float*)d_out;
    float* attn = y + (size_t)L * DMODEL;               // output 1 (fp32), 67.1M elems

    // ws layout (bf16 elems unless noted), 40 MB total:
    //   T0  [ 0, 8MB)  transposed weights (reused sequentially)
    //   qh  [ 8,16MB)  kh [16,24MB)  vhT [24,32MB)  O [32,40MB)
    //   ypre fp32 16MB overlays qh+kh (dead after the scores GEMM)
    const size_t SEG = (size_t)4194304;
    unsigned short* T0  = (unsigned short*)d_ws;
    unsigned short* qh  = T0 + SEG;
    unsigned short* kh  = qh + SEG;
    unsigned short* vhT = kh + SEG;
    unsigned short* O   = vhT + SEG;
    float* ypre = (float*)qh;

    const float inv_temper = 0.022097086912079608f;     // 1/sqrt(2048)
    dim3 tb(32, 8);

    // qh[h] = (q @ Wq[h]) / temper      (A fp32, M=2048,N=128,K=2048)
    transpose_f2b<<<dim3(4, 64, 16), tb, 0, stream>>>(Wq, T0, 2048, 128);
    gemm_bt<0, 1><<<dim3(1, 16, 16), 256, 0, stream>>>(q, T0, qh, 2048, 128, 2048,
        2048, 2048, 128, 0LL, 262144LL, 262144LL, inv_temper);
    // kh[h] = k @ Wk[h]
    transpose_f2b<<<dim3(4, 64, 16), tb, 0, stream>>>(Wk, T0, 2048, 128);
    gemm_bt<0, 1><<<dim3(1, 16, 16), 256, 0, stream>>>(k, T0, kh, 2048, 128, 2048,
        2048, 2048, 128, 0LL, 262144LL, 262144LL, 1.0f);
    // vhT[h] = (v @ Wv[h])^T  -> [vd][m]
    transpose_f2b<<<dim3(4, 64, 16), tb, 0, stream>>>(Wv, T0, 2048, 128);
    gemm_bt<1, 1><<<dim3(1, 16, 16), 256, 0, stream>>>(v, T0, vhT, 2048, 128, 2048,
        2048, 2048, 2048, 0LL, 262144LL, 262144LL, 1.0f);

    // logits[h] = qh[h] @ kh[h]^T  -> fp32 attn region (M=N=2048, K=128)
    gemm_bt<2, 0><<<dim3(16, 16, 16), 256, 0, stream>>>(qh, kh, attn, 2048, 2048, 128,
        128, 128, 2048, 262144LL, 262144LL, 4194304LL, 1.0f);

    // softmax over the query axis, in place (fp32)
    col_softmax<<<dim3(32, NH), dim3(64, 16), 0, stream>>>(attn);

    // O[l, h*128+vd] = attn[h] @ vh[h]   (A fp32)
    gemm_bt<0, 1><<<dim3(1, 16, 16), 256, 0, stream>>>(attn, vhT, O, 2048, 128, 2048,
        2048, 2048, 2048, 4194304LL, 262144LL, 128LL, 1.0f);

    // ypre = O @ proj_w   (fp32 out, M=N=K=2048)
    transpose_f2b<<<dim3(64, 64, 1), tb, 0, stream>>>(Pw, T0, 2048, 2048);
    gemm_bt<2, 0><<<dim3(16, 16, 1), 256, 0, stream>>>(O, T0, (void*)ypre, 2048, 2048, 2048,
        2048, 2048, 2048, 0LL, 0LL, 0LL, 1.0f);

    // y = LayerNorm(ypre + proj_b + residual) * g + b
    ln_resid<<<dim3(2048), 256, 0, stream>>>(ypre, q, Pb, Lg, Lb, y);
}

// Round 2
// 844.759 us; speedup vs baseline: 1.0994x; 1.0245x over previous
//
#include <hip/hip_runtime.h>
#include <stdint.h>

#define L 2048
#define DMODEL 2048
#define NH 16

typedef __bf16 bf16x8 __attribute__((ext_vector_type(8)));
typedef float f32x4 __attribute__((ext_vector_type(4)));
typedef short s16x4 __attribute__((ext_vector_type(4)));

__device__ __forceinline__ unsigned short f2bf(float f) {
    union { float f; unsigned int i; } w; w.f = f;
    unsigned int u = w.i;
    unsigned int r = u + 0x7fffu + ((u >> 16) & 1u);
    return (unsigned short)(r >> 16);
}

// ---------------------------------------------------------------------------
// Tiled bf16-MFMA GEMM, C = alpha * A (MxK) * B'(NxK)^T.  B' is B transposed
// (row n of B' holds column n of B, contiguous in K), always bf16.
// AF32=1: A is fp32 in memory, converted to bf16 (RNE) during LDS staging.
// CMODE 0: C bf16 row-major [m][n]   (ldc = row stride)
// CMODE 1: C bf16 transposed [n][m]  (ldc = row stride of transposed mat)
// CMODE 2: C fp32 row-major [m][n]
// BM: 128 (2x2 waves of 64x64, acc 4x4) or 64 (2x2 waves of 32x64, acc 2x4).
//   BM=64 doubles the grid for skinny/medium GEMMs: at 256 blocks the machine
//   sits at 1 block/CU (1 wave/SIMD) and every staging barrier stalls the CU.
// Grid (N/128, M/BM, batch), block 256 (4 waves).  lda/ldb/ldc/sA/sB/sC in
// ELEMENTS of the respective dtype.
// ---------------------------------------------------------------------------
template<int CMODE, int AF32, int BM>
__global__ __launch_bounds__(256, 2)
void gemm_bt(const void* __restrict__ Av,
             const unsigned short* __restrict__ B,
             void* __restrict__ C,
             int M, int N, int K, int lda, int ldb, int ldc,
             long long sA, long long sB, long long sC, float alpha)
{
    __shared__ unsigned short As[BM * 32];
    __shared__ unsigned short Bs[128 * 32];

    constexpr int AJ  = BM / 64;   // A 16B-chunks staged per thread
    constexpr int MFR = BM / 32;   // m-fragments per wave

    const int tid  = threadIdx.x;
    const int wave = tid >> 6;
    const int lane = tid & 63;
    const int quad = lane >> 4;
    const int l16  = lane & 15;

    const int tileN = blockIdx.x * 128;
    const int tileM = blockIdx.y * BM;

    const unsigned short* A16 = (const unsigned short*)Av + (AF32 ? 0 : (long long)blockIdx.z * sA);
    const float*          A32 = (const float*)Av          + (AF32 ? (long long)blockIdx.z * sA : 0);
    B += (long long)blockIdx.z * sB;

    const int wm = (wave >> 1) * (BM / 2);
    const int wn = (wave & 1) * 64;

    // 16B chunk ch -> row = ch>>2, k-offset = (ch&3)*8; LDS elem offset = ch*8.
    // B tile (128x32): 512 chunks, thread stages ch0=tid, ch1=tid+256.
    // A tile (BMx32): BM*4 chunks, thread stages tid + j*256 for j<AJ.
    const int ch0 = tid, ch1 = tid + 256;
    const int r0b = ch0 >> 2, kb0 = (ch0 & 3) * 8;
    const int r1b = ch1 >> 2, kb1 = (ch1 & 3) * 8;

    f32x4 acc[MFR][4] = {};

    for (int k0 = 0; k0 < K; k0 += 32) {
        int4 aR[AJ];
        #pragma unroll
        for (int j = 0; j < AJ; ++j) {
            const int ch = tid + j * 256;
            const int ra = ch >> 2, ka = (ch & 3) * 8;
            if (AF32) {
                const float* p = A32 + (long long)(tileM + ra) * lda + (k0 + ka);
                const float4 f0 = *(const float4*)p;
                const float4 f1 = *(const float4*)(p + 4);
                union { int4 v; unsigned short u[8]; } t;
                t.u[0] = f2bf(f0.x); t.u[1] = f2bf(f0.y); t.u[2] = f2bf(f0.z); t.u[3] = f2bf(f0.w);
                t.u[4] = f2bf(f1.x); t.u[5] = f2bf(f1.y); t.u[6] = f2bf(f1.z); t.u[7] = f2bf(f1.w);
                aR[j] = t.v;
            } else {
                aR[j] = *(const int4*)(A16 + (long long)(tileM + ra) * lda + (k0 + ka));
            }
        }
        const int4 b0 = *(const int4*)(B + (long long)(tileN + r0b) * ldb + (k0 + kb0));
        const int4 b1 = *(const int4*)(B + (long long)(tileN + r1b) * ldb + (k0 + kb1));

        __syncthreads();             // previous iteration's LDS reads complete
        #pragma unroll
        for (int j = 0; j < AJ; ++j)
            *(int4*)(As + (tid + j * 256) * 8) = aR[j];
        *(int4*)(Bs + ch0 * 8) = b0;
        *(int4*)(Bs + ch1 * 8) = b1;
        __syncthreads();             // staging visible

        bf16x8 af[MFR], bfr[4];
        #pragma unroll
        for (int i = 0; i < MFR; ++i)
            af[i] = *(const bf16x8*)(As + (wm + i * 16 + l16) * 32 + quad * 8);
        #pragma unroll
        for (int i = 0; i < 4; ++i)
            bfr[i] = *(const bf16x8*)(Bs + (wn + i * 16 + l16) * 32 + quad * 8);
        #pragma unroll
        for (int i = 0; i < MFR; ++i)
            #pragma unroll
            for (int j = 0; j < 4; ++j)
                acc[i][j] = __builtin_amdgcn_mfma_f32_16x16x32_bf16(af[i], bfr[j], acc[i][j], 0, 0, 0);
    }

    // Epilogue.  D layout: col = lane&15, row = quad*4 + reg   [m89-verified]
    const long long cb = (long long)blockIdx.z * sC;
    #pragma unroll
    for (int i = 0; i < MFR; ++i) {
        const int r0 = tileM + wm + i * 16 + quad * 4;
        #pragma unroll
        for (int j = 0; j < 4; ++j) {
            const int c = tileN + wn + j * 16 + l16;
            f32x4 d = acc[i][j];
            if (CMODE == 0) {
                unsigned short* Cp = (unsigned short*)C + cb;
                #pragma unroll
                for (int r = 0; r < 4; ++r)
                    Cp[(long long)(r0 + r) * ldc + c] = f2bf(d[r] * alpha);
            } else if (CMODE == 1) {
                unsigned short* Cp = (unsigned short*)C + cb + (long long)c * ldc + r0;
                s16x4 pk;
                #pragma unroll
                for (int r = 0; r < 4; ++r) pk[r] = (short)f2bf(d[r] * alpha);
                *(s16x4*)Cp = pk;
            } else {
                float* Cp = (float*)C + cb;
                #pragma unroll
                for (int r = 0; r < 4; ++r)
                    Cp[(long long)(r0 + r) * ldc + c] = d[r] * alpha;
            }
        }
    }
}

// ---------------------------------------------------------------------------
// 32x32 tile transpose, fp32 in -> bf16 out. Block (32,8).
// Grid (cols/32, rows/32, batch).  out[c][r] = bf16(in[r][c])
// ---------------------------------------------------------------------------
__global__ __launch_bounds__(256)
void transpose_f2b(const float* __restrict__ in, unsigned short* __restrict__ out,
                   int rows, int cols)
{
    __shared__ float t[32][33];
    const long long base = (long long)blockIdx.z * rows * cols;
    const int c0 = blockIdx.x * 32, r0 = blockIdx.y * 32;
    const int tx = threadIdx.x, ty0 = threadIdx.y;
    #pragma unroll
    for (int jj = 0; jj < 4; ++jj) {
        const int j = ty0 + jj * 8;
        t[j][tx] = in[base + (long long)(r0 + j) * cols + (c0 + tx)];
    }
    __syncthreads();
    #pragma unroll
    for (int jj = 0; jj < 4; ++jj) {
        const int j = ty0 + jj * 8;
        out[base + (long long)(c0 + j) * rows + (r0 + tx)] = f2bf(t[tx][j]);
    }
}

// ---------------------------------------------------------------------------
// Softmax over the QUERY axis (rows) of each head's row-major (Lq x Lk) fp32
// logits, in place.  Block (64 cols, 16 row-slices) = 1024 thr.
// Grid (Lk/64, NH) = (32, 16) = 512 blocks -> 2 blocks/CU on ALL 256 CUs.
// ---------------------------------------------------------------------------
__global__ __launch_bounds__(1024)
void col_softmax(float* __restrict__ S)
{
    __shared__ float shm[16][64], shl[16][64];
    const int tx = threadIdx.x, ty = threadIdx.y;
    const int c = blockIdx.x * 64 + tx;
    float* P = S + (long long)blockIdx.y * L * L + c;
    const int r0 = ty * (L / 16), r1 = r0 + (L / 16);

    float mmax = -1e30f, ssum = 0.f;
    for (int r = r0; r < r1; ++r) {
        float s = P[(long long)r * L];
        float mn = fmaxf(mmax, s);
        ssum = ssum * __expf(mmax - mn) + __expf(s - mn);
        mmax = mn;
    }
    shm[ty][tx] = mmax; shl[ty][tx] = ssum;
    __syncthreads();
    float M = -1e30f;
    #pragma unroll
    for (int t = 0; t < 16; ++t) M = fmaxf(M, shm[t][tx]);
    float Ls = 0.f;
    #pragma unroll
    for (int t = 0; t < 16; ++t) Ls += shl[t][tx] * __expf(shm[t][tx] - M);
    const float inv = 1.0f / Ls;
    for (int r = r0; r < r1; ++r) {
        float* p = P + (long long)r * L;
        *p = __expf(*p - M) * inv;
    }
}

// ---------------------------------------------------------------------------
// Residual + bias + LayerNorm (all fp32), one block (256 thr) per row of 2048.
// ---------------------------------------------------------------------------
__global__ __launch_bounds__(256)
void ln_resid(const float* __restrict__ ypre, const float* __restrict__ resid,
              const float* __restrict__ pb, const float* __restrict__ g,
              const float* __restrict__ bta, float* __restrict__ y)
{
    __shared__ float as_[4], as2_[4];
    const int l = blockIdx.x;
    const int tid = threadIdx.x;
    float v[8]; float s = 0.f, s2 = 0.f;
    #pragma unroll
    for (int i = 0; i < 8; ++i) {
        const int d = tid + i * 256;
        float t = ypre[(long long)l * DMODEL + d] + pb[d] + resid[(long long)l * DMODEL + d];
        v[i] = t; s += t; s2 += t * t;
    }
    #pragma unroll
    for (int off = 32; off > 0; off >>= 1) {
        s  += __shfl_down(s, off, 64);
        s2 += __shfl_down(s2, off, 64);
    }
    const int wave = tid >> 6, lane = tid & 63;
    if (lane == 0) { as_[wave] = s; as2_[wave] = s2; }
    __syncthreads();
    const float S  = as_[0] + as_[1] + as_[2] + as_[3];
    const float S2 = as2_[0] + as2_[1] + as2_[2] + as2_[3];
    const float mu  = S * (1.0f / DMODEL);
    const float var = S2 * (1.0f / DMODEL) - mu * mu;
    const float rs  = rsqrtf(var + 1e-5f);
    #pragma unroll
    for (int i = 0; i < 8; ++i) {
        const int d = tid + i * 256;
        y[(long long)l * DMODEL + d] = (v[i] - mu) * rs * g[d] + bta[d];
    }
}

// ---------------------------------------------------------------------------
extern "C" void kernel_launch(void* const* d_in, const int* in_sizes, int n_in,
                              void* d_out, int out_size, void* d_ws, size_t ws_size,
                              hipStream_t stream)
{
    const float* q  = (const float*)d_in[0];
    const float* k  = (const float*)d_in[1];
    const float* v  = (const float*)d_in[2];
    const float* Wq = (const float*)d_in[3];
    const float* Wk = (const float*)d_in[4];
    const float* Wv = (const float*)d_in[5];
    const float* Pw = (const float*)d_in[6];
    const float* Pb = (const float*)d_in[7];
    const float* Lg = (const float*)d_in[8];
    const float* Lb = (const float*)d_in[9];

    float* y    = (float*)d_out;
    float* attn = y + (size_t)L * DMODEL;               // output 1 (fp32), 67.1M elems

    // ws layout (bf16 elems unless noted), 40 MB total:
    //   T0  [ 0, 8MB)  transposed weights (reused sequentially)
    //   qh  [ 8,16MB)  kh [16,24MB)  vhT [24,32MB)  O [32,40MB)
    //   ypre fp32 16MB overlays qh+kh (dead after the scores GEMM)
    const size_t SEG = (size_t)4194304;
    unsigned short* T0  = (unsigned short*)d_ws;
    unsigned short* qh  = T0 + SEG;
    unsigned short* kh  = qh + SEG;
    unsigned short* vhT = kh + SEG;
    unsigned short* O   = vhT + SEG;
    float* ypre = (float*)qh;

    const float inv_temper = 0.022097086912079608f;     // 1/sqrt(2048)
    dim3 tb(32, 8);

    // qh[h] = (q @ Wq[h]) / temper      (A fp32, M=2048,N=128,K=2048)
    transpose_f2b<<<dim3(4, 64, 16), tb, 0, stream>>>(Wq, T0, 2048, 128);
    gemm_bt<0, 1, 64><<<dim3(1, 32, 16), 256, 0, stream>>>(q, T0, qh, 2048, 128, 2048,
        2048, 2048, 128, 0LL, 262144LL, 262144LL, inv_temper);
    // kh[h] = k @ Wk[h]
    transpose_f2b<<<dim3(4, 64, 16), tb, 0, stream>>>(Wk, T0, 2048, 128);
    gemm_bt<0, 1, 64><<<dim3(1, 32, 16), 256, 0, stream>>>(k, T0, kh, 2048, 128, 2048,
        2048, 2048, 128, 0LL, 262144LL, 262144LL, 1.0f);
    // vhT[h] = (v @ Wv[h])^T  -> [vd][m]
    transpose_f2b<<<dim3(4, 64, 16), tb, 0, stream>>>(Wv, T0, 2048, 128);
    gemm_bt<1, 1, 64><<<dim3(1, 32, 16), 256, 0, stream>>>(v, T0, vhT, 2048, 128, 2048,
        2048, 2048, 2048, 0LL, 262144LL, 262144LL, 1.0f);

    // logits[h] = qh[h] @ kh[h]^T  -> fp32 attn region (M=N=2048, K=128)
    gemm_bt<2, 0, 128><<<dim3(16, 16, 16), 256, 0, stream>>>(qh, kh, attn, 2048, 2048, 128,
        128, 128, 2048, 262144LL, 262144LL, 4194304LL, 1.0f);

    // softmax over the query axis, in place (fp32)
    col_softmax<<<dim3(32, NH), dim3(64, 16), 0, stream>>>(attn);

    // O[l, h*128+vd] = attn[h] @ vh[h]   (A fp32)
    gemm_bt<0, 1, 64><<<dim3(1, 32, 16), 256, 0, stream>>>(attn, vhT, O, 2048, 128, 2048,
        2048, 2048, 2048, 4194304LL, 262144LL, 128LL, 1.0f);

    // ypre = O @ proj_w   (fp32 out, M=N=K=2048)
    transpose_f2b<<<dim3(64, 64, 1), tb, 0, stream>>>(Pw, T0, 2048, 2048);
    gemm_bt<2, 0, 64><<<dim3(16, 32, 1), 256, 0, stream>>>(O, T0, (void*)ypre, 2048, 2048, 2048,
        2048, 2048, 2048, 0LL, 0LL, 0LL, 1.0f);

    // y = LayerNorm(ypre + proj_b + residual) * g + b
    ln_resid<<<dim3(2048), 256, 0, stream>>>(ypre, q, Pb, Lg, Lb, y);
}

// Round 3
// 743.152 us; speedup vs baseline: 1.2497x; 1.1367x over previous
//
#include <hip/hip_runtime.h>
#include <stdint.h>

#define L 2048
#define DMODEL 2048
#define NH 16

typedef __bf16 bf16x8 __attribute__((ext_vector_type(8)));
typedef float f32x4 __attribute__((ext_vector_type(4)));
typedef short s16x4 __attribute__((ext_vector_type(4)));

__device__ __forceinline__ unsigned short f2bf(float f) {
    union { float f; unsigned int i; } w; w.f = f;
    unsigned int u = w.i;
    unsigned int r = u + 0x7fffu + ((u >> 16) & 1u);
    return (unsigned short)(r >> 16);
}

// Async global->LDS, 16 bytes per lane.  LDS dest must be wave-uniform base +
// lane*16 (m104) -- our staging layout satisfies this (thread tid writes
// LDS offset tid*16B within a contiguous region).
__device__ __forceinline__ void gload_lds16(const unsigned short* g, unsigned short* l) {
    __builtin_amdgcn_global_load_lds(
        (const __attribute__((address_space(1))) void*)g,
        (__attribute__((address_space(3))) void*)l, 16, 0, 0);
}

// ---------------------------------------------------------------------------
// Tiled bf16-MFMA GEMM, C = alpha * A (MxK) * B'(NxK)^T.  B' is B transposed
// (row n of B' holds column n of B, contiguous in K), always bf16.
// AF32=1: A is fp32 in memory, converted to bf16 (RNE) during LDS staging
//         (register path).  AF32=0: A is bf16, staged via global_load_lds.
// CMODE 0: C bf16 row-major [m][n]   (ldc = row stride)
// CMODE 1: C bf16 transposed [n][m]  (ldc = row stride of transposed mat)
// CMODE 2: C fp32 row-major [m][n]
// CMODE 3: fused QKV mode: z<32 -> mode0 (ldc=128, alpha for z<16 only),
//          z>=32 -> mode1 (ldc=2048).  A base advances by sA per z>>4.
// BM: 128 (waves 64x64, acc 4x4) or 64 (waves 32x64, acc 2x4).
// Grid (N/128, M/BM, batch), block 256 (4 waves).  lda/ldb/ldc/sA/sB/sC in
// ELEMENTS of the respective dtype.
// ---------------------------------------------------------------------------
template<int CMODE, int AF32, int BM>
__global__ __launch_bounds__(256, 2)
void gemm_bt(const void* __restrict__ Av,
             const unsigned short* __restrict__ B,
             void* __restrict__ C,
             int M, int N, int K, int lda, int ldb, int ldc,
             long long sA, long long sB, long long sC, float alpha)
{
    __shared__ unsigned short As[BM * 32];
    __shared__ unsigned short Bs[128 * 32];

    constexpr int AJ  = BM / 64;   // A 16B-chunks staged per thread
    constexpr int MFR = BM / 32;   // m-fragments per wave

    const int tid  = threadIdx.x;
    const int wave = tid >> 6;
    const int lane = tid & 63;
    const int quad = lane >> 4;
    const int l16  = lane & 15;

    const int tileN = blockIdx.x * 128;
    const int tileM = blockIdx.y * BM;

    const long long zA = (CMODE == 3) ? (long long)(blockIdx.z >> 4) : (long long)blockIdx.z;
    const unsigned short* A16 = (const unsigned short*)Av + (AF32 ? 0 : zA * sA);
    const float*          A32 = (const float*)Av          + (AF32 ? zA * sA : 0);
    B += (long long)blockIdx.z * sB;

    const int wm = (wave >> 1) * (BM / 2);
    const int wn = (wave & 1) * 64;

    // 16B chunk ch -> row = ch>>2, k-offset = (ch&3)*8; LDS elem offset = ch*8.
    const int ch0 = tid, ch1 = tid + 256;
    const int r0b = ch0 >> 2, kb0 = (ch0 & 3) * 8;
    const int r1b = ch1 >> 2, kb1 = (ch1 & 3) * 8;

    f32x4 acc[MFR][4] = {};

    for (int k0 = 0; k0 < K; k0 += 32) {
        int4 aR[AJ];
        if (AF32) {
            #pragma unroll
            for (int j = 0; j < AJ; ++j) {
                const int ch = tid + j * 256;
                const int ra = ch >> 2, ka = (ch & 3) * 8;
                const float* p = A32 + (long long)(tileM + ra) * lda + (k0 + ka);
                const float4 f0 = *(const float4*)p;
                const float4 f1 = *(const float4*)(p + 4);
                union { int4 v; unsigned short u[8]; } t;
                t.u[0] = f2bf(f0.x); t.u[1] = f2bf(f0.y); t.u[2] = f2bf(f0.z); t.u[3] = f2bf(f0.w);
                t.u[4] = f2bf(f1.x); t.u[5] = f2bf(f1.y); t.u[6] = f2bf(f1.z); t.u[7] = f2bf(f1.w);
                aR[j] = t.v;
            }
        }

        __syncthreads();             // previous iteration's LDS reads complete
        if (AF32) {
            #pragma unroll
            for (int j = 0; j < AJ; ++j)
                *(int4*)(As + (tid + j * 256) * 8) = aR[j];
        } else {
            #pragma unroll
            for (int j = 0; j < AJ; ++j) {
                const int ch = tid + j * 256;
                const int ra = ch >> 2, ka = (ch & 3) * 8;
                gload_lds16(A16 + (long long)(tileM + ra) * lda + (k0 + ka), As + ch * 8);
            }
        }
        gload_lds16(B + (long long)(tileN + r0b) * ldb + (k0 + kb0), Bs + ch0 * 8);
        gload_lds16(B + (long long)(tileN + r1b) * ldb + (k0 + kb1), Bs + ch1 * 8);
        __syncthreads();             // staging visible (vmcnt+lgkm drained)

        bf16x8 af[MFR], bfr[4];
        #pragma unroll
        for (int i = 0; i < MFR; ++i)
            af[i] = *(const bf16x8*)(As + (wm + i * 16 + l16) * 32 + quad * 8);
        #pragma unroll
        for (int i = 0; i < 4; ++i)
            bfr[i] = *(const bf16x8*)(Bs + (wn + i * 16 + l16) * 32 + quad * 8);
        #pragma unroll
        for (int i = 0; i < MFR; ++i)
            #pragma unroll
            for (int j = 0; j < 4; ++j)
                acc[i][j] = __builtin_amdgcn_mfma_f32_16x16x32_bf16(af[i], bfr[j], acc[i][j], 0, 0, 0);
    }

    // Epilogue.  D layout: col = lane&15, row = quad*4 + reg   [m89-verified]
    const long long cb = (long long)blockIdx.z * sC;
    const float aEff = (CMODE == 3) ? (blockIdx.z < 16 ? alpha : 1.0f) : alpha;
    #pragma unroll
    for (int i = 0; i < MFR; ++i) {
        const int r0 = tileM + wm + i * 16 + quad * 4;
        #pragma unroll
        for (int j = 0; j < 4; ++j) {
            const int c = tileN + wn + j * 16 + l16;
            f32x4 d = acc[i][j];
            if (CMODE == 0) {
                unsigned short* Cp = (unsigned short*)C + cb;
                #pragma unroll
                for (int r = 0; r < 4; ++r)
                    Cp[(long long)(r0 + r) * ldc + c] = f2bf(d[r] * aEff);
            } else if (CMODE == 1) {
                unsigned short* Cp = (unsigned short*)C + cb + (long long)c * ldc + r0;
                s16x4 pk;
                #pragma unroll
                for (int r = 0; r < 4; ++r) pk[r] = (short)f2bf(d[r] * aEff);
                *(s16x4*)Cp = pk;
            } else if (CMODE == 2) {
                float* Cp = (float*)C + cb;
                #pragma unroll
                for (int r = 0; r < 4; ++r)
                    Cp[(long long)(r0 + r) * ldc + c] = d[r] * aEff;
            } else { // CMODE 3: fused QKV
                if (blockIdx.z < 32) {          // qh/kh, bf16 row-major, ldc=128
                    unsigned short* Cp = (unsigned short*)C + cb;
                    #pragma unroll
                    for (int r = 0; r < 4; ++r)
                        Cp[(long long)(r0 + r) * 128 + c] = f2bf(d[r] * aEff);
                } else {                         // vhT, bf16 transposed, ldc=2048
                    unsigned short* Cp = (unsigned short*)C + cb + (long long)c * 2048 + r0;
                    s16x4 pk;
                    #pragma unroll
                    for (int r = 0; r < 4; ++r) pk[r] = (short)f2bf(d[r]);
                    *(s16x4*)Cp = pk;
                }
            }
        }
    }
}

// ---------------------------------------------------------------------------
// fp32 -> bf16 elementwise for q,k,v (z selects input).  8 elems/thread.
// Grid (2048, 1, 3), block 256.  out[z] contiguous at z*4194304.
// ---------------------------------------------------------------------------
__global__ __launch_bounds__(256)
void cvt_f2b3(const float* __restrict__ a, const float* __restrict__ b,
              const float* __restrict__ c, unsigned short* __restrict__ out)
{
    const float* in = blockIdx.z == 0 ? a : blockIdx.z == 1 ? b : c;
    const long long i = ((long long)blockIdx.x * 256 + threadIdx.x) * 8;
    const float4 f0 = *(const float4*)(in + i);
    const float4 f1 = *(const float4*)(in + i + 4);
    union { int4 v; unsigned short u[8]; } t;
    t.u[0] = f2bf(f0.x); t.u[1] = f2bf(f0.y); t.u[2] = f2bf(f0.z); t.u[3] = f2bf(f0.w);
    t.u[4] = f2bf(f1.x); t.u[5] = f2bf(f1.y); t.u[6] = f2bf(f1.z); t.u[7] = f2bf(f1.w);
    *(int4*)(out + (long long)blockIdx.z * 4194304 + i) = t.v;
}

// ---------------------------------------------------------------------------
// 32x32 tile transpose, fp32 in -> bf16 out. Block (32,8).
// Grid (cols/32, rows/32, batch).  out[c][r] = bf16(in[r][c])
// ---------------------------------------------------------------------------
__global__ __launch_bounds__(256)
void transpose_f2b(const float* __restrict__ in, unsigned short* __restrict__ out,
                   int rows, int cols)
{
    __shared__ float t[32][33];
    const long long base = (long long)blockIdx.z * rows * cols;
    const int c0 = blockIdx.x * 32, r0 = blockIdx.y * 32;
    const int tx = threadIdx.x, ty0 = threadIdx.y;
    #pragma unroll
    for (int jj = 0; jj < 4; ++jj) {
        const int j = ty0 + jj * 8;
        t[j][tx] = in[base + (long long)(r0 + j) * cols + (c0 + tx)];
    }
    __syncthreads();
    #pragma unroll
    for (int jj = 0; jj < 4; ++jj) {
        const int j = ty0 + jj * 8;
        out[base + (long long)(c0 + j) * rows + (r0 + tx)] = f2bf(t[tx][j]);
    }
}

// Fused Wq/Wk/Wv transpose: z in [0,48), widx=z>>4 picks the weight, h=z&15.
__global__ __launch_bounds__(256)
void transpose_f2b3(const float* __restrict__ Wq, const float* __restrict__ Wk,
                    const float* __restrict__ Wv, unsigned short* __restrict__ out)
{
    __shared__ float t[32][33];
    const int z = blockIdx.z, widx = z >> 4, h = z & 15;
    const float* in = (widx == 0 ? Wq : widx == 1 ? Wk : Wv) + (long long)h * 2048 * 128;
    unsigned short* o = out + (long long)z * 262144;
    const int c0 = blockIdx.x * 32, r0 = blockIdx.y * 32;
    const int tx = threadIdx.x, ty0 = threadIdx.y;
    #pragma unroll
    for (int jj = 0; jj < 4; ++jj) {
        const int j = ty0 + jj * 8;
        t[j][tx] = in[(long long)(r0 + j) * 128 + (c0 + tx)];
    }
    __syncthreads();
    #pragma unroll
    for (int jj = 0; jj < 4; ++jj) {
        const int j = ty0 + jj * 8;
        o[(long long)(c0 + j) * 2048 + (r0 + tx)] = f2bf(t[tx][j]);
    }
}

// ---------------------------------------------------------------------------
// Softmax over the QUERY axis (rows) of each head's row-major (Lq x Lk) fp32
// logits, in place.  Block (64 cols, 16 row-slices) = 1024 thr.
// Grid (Lk/64, NH) = (32, 16) = 512 blocks -> 2 blocks/CU on ALL 256 CUs.
// ---------------------------------------------------------------------------
__global__ __launch_bounds__(1024)
void col_softmax(float* __restrict__ S)
{
    __shared__ float shm[16][64], shl[16][64];
    const int tx = threadIdx.x, ty = threadIdx.y;
    const int c = blockIdx.x * 64 + tx;
    float* P = S + (long long)blockIdx.y * L * L + c;
    const int r0 = ty * (L / 16), r1 = r0 + (L / 16);

    float mmax = -1e30f, ssum = 0.f;
    for (int r = r0; r < r1; ++r) {
        float s = P[(long long)r * L];
        float mn = fmaxf(mmax, s);
        ssum = ssum * __expf(mmax - mn) + __expf(s - mn);
        mmax = mn;
    }
    shm[ty][tx] = mmax; shl[ty][tx] = ssum;
    __syncthreads();
    float M = -1e30f;
    #pragma unroll
    for (int t = 0; t < 16; ++t) M = fmaxf(M, shm[t][tx]);
    float Ls = 0.f;
    #pragma unroll
    for (int t = 0; t < 16; ++t) Ls += shl[t][tx] * __expf(shm[t][tx] - M);
    const float inv = 1.0f / Ls;
    for (int r = r0; r < r1; ++r) {
        float* p = P + (long long)r * L;
        *p = __expf(*p - M) * inv;
    }
}

// ---------------------------------------------------------------------------
// Residual + bias + LayerNorm (all fp32), one block (256 thr) per row of 2048.
// ---------------------------------------------------------------------------
__global__ __launch_bounds__(256)
void ln_resid(const float* __restrict__ ypre, const float* __restrict__ resid,
              const float* __restrict__ pb, const float* __restrict__ g,
              const float* __restrict__ bta, float* __restrict__ y)
{
    __shared__ float as_[4], as2_[4];
    const int l = blockIdx.x;
    const int tid = threadIdx.x;
    float v[8]; float s = 0.f, s2 = 0.f;
    #pragma unroll
    for (int i = 0; i < 8; ++i) {
        const int d = tid + i * 256;
        float t = ypre[(long long)l * DMODEL + d] + pb[d] + resid[(long long)l * DMODEL + d];
        v[i] = t; s += t; s2 += t * t;
    }
    #pragma unroll
    for (int off = 32; off > 0; off >>= 1) {
        s  += __shfl_down(s, off, 64);
        s2 += __shfl_down(s2, off, 64);
    }
    const int wave = tid >> 6, lane = tid & 63;
    if (lane == 0) { as_[wave] = s; as2_[wave] = s2; }
    __syncthreads();
    const float S  = as_[0] + as_[1] + as_[2] + as_[3];
    const float S2 = as2_[0] + as2_[1] + as2_[2] + as2_[3];
    const float mu  = S * (1.0f / DMODEL);
    const float var = S2 * (1.0f / DMODEL) - mu * mu;
    const float rs  = rsqrtf(var + 1e-5f);
    #pragma unroll
    for (int i = 0; i < 8; ++i) {
        const int d = tid + i * 256;
        y[(long long)l * DMODEL + d] = (v[i] - mu) * rs * g[d] + bta[d];
    }
}

// ---------------------------------------------------------------------------
extern "C" void kernel_launch(void* const* d_in, const int* in_sizes, int n_in,
                              void* d_out, int out_size, void* d_ws, size_t ws_size,
                              hipStream_t stream)
{
    const float* q  = (const float*)d_in[0];
    const float* k  = (const float*)d_in[1];
    const float* v  = (const float*)d_in[2];
    const float* Wq = (const float*)d_in[3];
    const float* Wk = (const float*)d_in[4];
    const float* Wv = (const float*)d_in[5];
    const float* Pw = (const float*)d_in[6];
    const float* Pb = (const float*)d_in[7];
    const float* Lg = (const float*)d_in[8];
    const float* Lb = (const float*)d_in[9];

    float* y    = (float*)d_out;
    float* attn = y + (size_t)L * DMODEL;               // output 1 (fp32), 268 MB

    // ws layout (bf16 elems), 40 MB:
    //   T0 [0,8MB) (Pw^T), qh [8,16), kh [16,24), vhT [24,32), O [32,40)
    //   ypre fp32 overlays qh+kh (dead after the scores GEMM).
    // The attn output region (268 MB) is dead until the scores GEMM writes it,
    // so the bf16 copies of q,k,v (24 MB) and Wq/Wk/Wv^T (24 MB) are stashed
    // there and consumed by the fused projection GEMM beforehand.
    const size_t SEG = (size_t)4194304;
    unsigned short* T0  = (unsigned short*)d_ws;
    unsigned short* qh  = T0 + SEG;
    unsigned short* kh  = qh + SEG;
    unsigned short* vhT = kh + SEG;
    unsigned short* O   = vhT + SEG;
    float* ypre = (float*)qh;

    unsigned short* qkvb = (unsigned short*)attn;       // qb,kb,vb: 3 x SEG
    unsigned short* WT   = qkvb + 3 * SEG;              // WqT,WkT,WvT: 48 heads x 262144

    const float inv_temper = 0.022097086912079608f;     // 1/sqrt(2048)
    dim3 tb(32, 8);

    // Stage 0: bf16-ify q,k,v; transpose all three weights (one launch each).
    cvt_f2b3<<<dim3(2048, 1, 3), 256, 0, stream>>>(q, k, v, qkvb);
    transpose_f2b3<<<dim3(4, 64, 48), tb, 0, stream>>>(Wq, Wk, Wv, WT);

    // Stage 1: fused Q/K/V projections, one launch, z = 48 (3 x 16 heads).
    // z<16: qh (alpha=1/temper), z<32: kh, z>=32: vhT (transposed C).
    // A = qkvb + (z>>4)*SEG; B = WT + z*262144; C = qh + z*262144
    // (qh,kh,vhT are contiguous, so one base covers all three).
    gemm_bt<3, 0, 64><<<dim3(1, 32, 48), 256, 0, stream>>>(qkvb, WT, qh,
        2048, 128, 2048, 2048, 2048, 0, 4194304LL, 262144LL, 262144LL, inv_temper);

    // logits[h] = qh[h] @ kh[h]^T  -> fp32 attn region (M=N=2048, K=128)
    gemm_bt<2, 0, 128><<<dim3(16, 16, 16), 256, 0, stream>>>(qh, kh, attn, 2048, 2048, 128,
        128, 128, 2048, 262144LL, 262144LL, 4194304LL, 1.0f);

    // softmax over the query axis, in place (fp32)
    col_softmax<<<dim3(32, NH), dim3(64, 16), 0, stream>>>(attn);

    // O[l, h*128+vd] = attn[h] @ vh[h]   (A fp32 runtime -> register staging)
    gemm_bt<0, 1, 64><<<dim3(1, 32, 16), 256, 0, stream>>>(attn, vhT, O, 2048, 128, 2048,
        2048, 2048, 2048, 4194304LL, 262144LL, 128LL, 1.0f);

    // ypre = O @ proj_w   (fp32 out, M=N=K=2048)
    transpose_f2b<<<dim3(64, 64, 1), tb, 0, stream>>>(Pw, T0, 2048, 2048);
    gemm_bt<2, 0, 64><<<dim3(16, 32, 1), 256, 0, stream>>>(O, T0, (void*)ypre, 2048, 2048, 2048,
        2048, 2048, 2048, 0LL, 0LL, 0LL, 1.0f);

    // y = LayerNorm(ypre + proj_b + residual) * g + b
    ln_resid<<<dim3(2048), 256, 0, stream>>>(ypre, q, Pb, Lg, Lb, y);
}

// Round 4
// 700.635 us; speedup vs baseline: 1.3256x; 1.0607x over previous
//
#include <hip/hip_runtime.h>
#include <stdint.h>

#define L 2048
#define DMODEL 2048
#define NH 16

typedef __bf16 bf16x8 __attribute__((ext_vector_type(8)));
typedef float f32x4 __attribute__((ext_vector_type(4)));
typedef short s16x4 __attribute__((ext_vector_type(4)));

__device__ __forceinline__ unsigned short f2bf(float f) {
    union { float f; unsigned int i; } w; w.f = f;
    unsigned int u = w.i;
    unsigned int r = u + 0x7fffu + ((u >> 16) & 1u);
    return (unsigned short)(r >> 16);
}

// Async global->LDS, 16 bytes per lane.  LDS dest is wave-uniform base +
// lane*16 (m104) -- thread tid writes LDS offset tid*16B, contiguous.
__device__ __forceinline__ void gload_lds16(const unsigned short* g, unsigned short* l) {
    __builtin_amdgcn_global_load_lds(
        (const __attribute__((address_space(1))) void*)g,
        (__attribute__((address_space(3))) void*)l, 16, 0, 0);
}

// ---------------------------------------------------------------------------
// Tiled bf16-MFMA GEMM, C = alpha * A (MxK) * B'(NxK)^T.  B' is B transposed
// (row n of B' holds column n of B, contiguous in K), always bf16, staged via
// global_load_lds.  Double-buffered LDS, ONE __syncthreads per K-step: stage
// of tile t+1 is issued before compute of tile t (T3-minimum pipeline; the
// barrier retains full-drain semantics so this is race-free code motion).
// AMODE 0: A bf16, global_load_lds staging.
// AMODE 2: A fp32 logits; staging applies column-softmax normalize
//          p = exp(s - Mg[col]) * iLg[col], writes p back to Awr IN PLACE
//          (each element staged exactly once: gridDim.x==1), feeds bf16(p)
//          to MFMA.  Requires BM=64 (AJ==1).
// CMODE 0: C bf16 row-major [m][n]   (ldc = row stride)
// CMODE 1: C bf16 transposed [n][m]
// CMODE 2: C fp32 row-major [m][n]
// CMODE 3: fused QKV: z<32 -> mode0 (ldc=128, alpha for z<16), z>=32 ->
//          mode1 (ldc=2048).  A base advances by sA per z>>4.
// PSM 1 (CMODE 2 only): epilogue also emits per-block column-softmax partials
//   pPart[(z*16+by)*2048 + col] = max over the block's 128 rows,
//   pPart[+16*16*2048]          = sum exp(s - max)   (for the query-axis SM).
// Grid (N/128, M/BM, batch), block 256 (4 waves).
// ---------------------------------------------------------------------------
template<int CMODE, int AMODE, int BM, int PSM>
__global__ __launch_bounds__(256, 2)
void gemm_bt(const void* Av,
             const unsigned short* __restrict__ B,
             void* __restrict__ C,
             int M, int N, int K, int lda, int ldb, int ldc,
             long long sA, long long sB, long long sC, float alpha,
             const float* __restrict__ Mg, const float* __restrict__ iLg,
             float* Awr, float* __restrict__ pPart)
{
    static_assert(AMODE != 2 || BM == 64, "softmax-A path assumes BM==64");
    __shared__ unsigned short As[2][BM * 32];
    __shared__ unsigned short Bs[2][128 * 32];

    constexpr int AJ  = BM / 64;   // A 16B-chunks staged per thread
    constexpr int MFR = BM / 32;   // m-fragments per wave

    const int tid  = threadIdx.x;
    const int wave = tid >> 6;
    const int lane = tid & 63;
    const int quad = lane >> 4;
    const int l16  = lane & 15;

    const int tileN = blockIdx.x * 128;
    const int tileM = blockIdx.y * BM;

    const long long zA = (CMODE == 3) ? (long long)(blockIdx.z >> 4) : (long long)blockIdx.z;
    const unsigned short* A16 = (const unsigned short*)Av + zA * sA;
    const float*          A32 = (const float*)Av + zA * sA;
    B += (long long)blockIdx.z * sB;

    const int wm = (wave >> 1) * (BM / 2);
    const int wn = (wave & 1) * 64;

    // 16B chunk ch -> row = ch>>2, k-offset = (ch&3)*8; LDS elem offset = ch*8.
    const int ch0 = tid, ch1 = tid + 256;
    const int r0b = ch0 >> 2, kb0 = (ch0 & 3) * 8;
    const int r1b = ch1 >> 2, kb1 = (ch1 & 3) * 8;

    // -------- staging helpers --------
    float4 f0, f1, m0, m1, l0, l1;     // AMODE2 in-flight A values
    long long aidx = 0;

    auto stageB = [&](int kk, int buf) {
        gload_lds16(B + (long long)(tileN + r0b) * ldb + (kk + kb0), &Bs[buf][ch0 * 8]);
        gload_lds16(B + (long long)(tileN + r1b) * ldb + (kk + kb1), &Bs[buf][ch1 * 8]);
    };
    auto stageA_gl = [&](int kk, int buf) {
        #pragma unroll
        for (int j = 0; j < AJ; ++j) {
            const int ch = tid + j * 256;
            const int ra = ch >> 2, ka = (ch & 3) * 8;
            gload_lds16(A16 + (long long)(tileM + ra) * lda + (kk + ka), &As[buf][ch * 8]);
        }
    };
    auto loadA_sm = [&](int kk) {       // issue loads (early)
        const int ra = tid >> 2, ka = (tid & 3) * 8;
        aidx = (long long)(tileM + ra) * lda + (kk + ka);
        const float* p = A32 + aidx;
        f0 = *(const float4*)p;  f1 = *(const float4*)(p + 4);
        const long long sb = (long long)blockIdx.z * 2048 + (kk + ka);
        m0 = *(const float4*)(Mg + sb);  m1 = *(const float4*)(Mg + sb + 4);
        l0 = *(const float4*)(iLg + sb); l1 = *(const float4*)(iLg + sb + 4);
    };
    auto finA_sm = [&](int buf) {       // normalize + writeback + LDS (late)
        f0.x = __expf(f0.x - m0.x) * l0.x;  f0.y = __expf(f0.y - m0.y) * l0.y;
        f0.z = __expf(f0.z - m0.z) * l0.z;  f0.w = __expf(f0.w - m0.w) * l0.w;
        f1.x = __expf(f1.x - m1.x) * l1.x;  f1.y = __expf(f1.y - m1.y) * l1.y;
        f1.z = __expf(f1.z - m1.z) * l1.z;  f1.w = __expf(f1.w - m1.w) * l1.w;
        float* wb = Awr + (long long)blockIdx.z * sA + aidx;
        *(float4*)wb = f0;  *(float4*)(wb + 4) = f1;
        union { int4 v; unsigned short u[8]; } tt;
        tt.u[0] = f2bf(f0.x); tt.u[1] = f2bf(f0.y); tt.u[2] = f2bf(f0.z); tt.u[3] = f2bf(f0.w);
        tt.u[4] = f2bf(f1.x); tt.u[5] = f2bf(f1.y); tt.u[6] = f2bf(f1.z); tt.u[7] = f2bf(f1.w);
        *(int4*)(&As[buf][tid * 8]) = tt.v;
    };

    f32x4 acc[MFR][4] = {};
    const int nt = K / 32;

    // -------- prologue: stage tile 0 into buffer 0 --------
    if constexpr (AMODE == 0) {
        stageA_gl(0, 0);
    } else {
        loadA_sm(0);
        finA_sm(0);
    }
    stageB(0, 0);
    __syncthreads();

    int cur = 0;
    for (int t = 0; t < nt; ++t) {
        const int nxt = cur ^ 1;
        const int k0n = (t + 1) * 32;
        const bool pf = (t + 1 < nt);

        // issue next-tile staging BEFORE compute (latency hides under MFMA)
        if (pf) {
            if constexpr (AMODE == 0) stageA_gl(k0n, nxt);
            else                      loadA_sm(k0n);
            stageB(k0n, nxt);
        }

        // compute current tile
        bf16x8 af[MFR], bfr[4];
        #pragma unroll
        for (int i = 0; i < MFR; ++i)
            af[i] = *(const bf16x8*)(&As[cur][(wm + i * 16 + l16) * 32 + quad * 8]);
        #pragma unroll
        for (int i = 0; i < 4; ++i)
            bfr[i] = *(const bf16x8*)(&Bs[cur][(wn + i * 16 + l16) * 32 + quad * 8]);
        #pragma unroll
        for (int i = 0; i < MFR; ++i)
            #pragma unroll
            for (int j = 0; j < 4; ++j)
                acc[i][j] = __builtin_amdgcn_mfma_f32_16x16x32_bf16(af[i], bfr[j], acc[i][j], 0, 0, 0);

        if constexpr (AMODE == 2) { if (pf) finA_sm(nxt); }

        __syncthreads();             // drains vmcnt+lgkm: next staged, cur reads done
        cur = nxt;
    }

    // -------- epilogue.  D layout: col = lane&15, row = quad*4+reg [m89] ----
    const long long cb = (long long)blockIdx.z * sC;
    const float aEff = (CMODE == 3) ? (blockIdx.z < 16 ? alpha : 1.0f) : alpha;
    #pragma unroll
    for (int i = 0; i < MFR; ++i) {
        const int r0 = tileM + wm + i * 16 + quad * 4;
        #pragma unroll
        for (int j = 0; j < 4; ++j) {
            const int c = tileN + wn + j * 16 + l16;
            f32x4 d = acc[i][j];
            if (CMODE == 0) {
                unsigned short* Cp = (unsigned short*)C + cb;
                #pragma unroll
                for (int r = 0; r < 4; ++r)
                    Cp[(long long)(r0 + r) * ldc + c] = f2bf(d[r] * aEff);
            } else if (CMODE == 1) {
                unsigned short* Cp = (unsigned short*)C + cb + (long long)c * ldc + r0;
                s16x4 pk;
                #pragma unroll
                for (int r = 0; r < 4; ++r) pk[r] = (short)f2bf(d[r] * aEff);
                *(s16x4*)Cp = pk;
            } else if (CMODE == 2) {
                float* Cp = (float*)C + cb;
                #pragma unroll
                for (int r = 0; r < 4; ++r)
                    Cp[(long long)(r0 + r) * ldc + c] = d[r] * aEff;
            } else { // CMODE 3: fused QKV
                if (blockIdx.z < 32) {          // qh/kh, bf16 row-major, ldc=128
                    unsigned short* Cp = (unsigned short*)C + cb;
                    #pragma unroll
                    for (int r = 0; r < 4; ++r)
                        Cp[(long long)(r0 + r) * 128 + c] = f2bf(d[r] * aEff);
                } else {                         // vhT, bf16 transposed, ldc=2048
                    unsigned short* Cp = (unsigned short*)C + cb + (long long)c * 2048 + r0;
                    s16x4 pk;
                    #pragma unroll
                    for (int r = 0; r < 4; ++r) pk[r] = (short)f2bf(d[r]);
                    *(s16x4*)Cp = pk;
                }
            }
        }
    }

    // -------- column-softmax partials (query-axis SM, alpha==1 here) --------
    if constexpr (PSM) {
        __shared__ float shPm[2][128], shPe[2][128];
        const int wmh = wave >> 1;
        #pragma unroll
        for (int j = 0; j < 4; ++j) {
            float mj = -1e30f;
            #pragma unroll
            for (int i = 0; i < MFR; ++i)
                #pragma unroll
                for (int r = 0; r < 4; ++r) mj = fmaxf(mj, acc[i][j][r]);
            float ej = 0.f;
            #pragma unroll
            for (int i = 0; i < MFR; ++i)
                #pragma unroll
                for (int r = 0; r < 4; ++r) ej += __expf(acc[i][j][r] - mj);
            #pragma unroll
            for (int off = 16; off < 64; off <<= 1) {   // reduce across quads
                float mo = __shfl_xor(mj, off, 64);
                float eo = __shfl_xor(ej, off, 64);
                float mn = fmaxf(mj, mo);
                ej = ej * __expf(mj - mn) + eo * __expf(mo - mn);
                mj = mn;
            }
            if (quad == 0) {
                shPm[wmh][wn + j * 16 + l16] = mj;
                shPe[wmh][wn + j * 16 + l16] = ej;
            }
        }
        __syncthreads();
        if (tid < 128) {
            const float mA = shPm[0][tid], mB = shPm[1][tid];
            const float m = fmaxf(mA, mB);
            const float e = shPe[0][tid] * __expf(mA - m) + shPe[1][tid] * __expf(mB - m);
            const long long pidx = ((long long)blockIdx.z * 16 + blockIdx.y) * 2048 + tileN + tid;
            pPart[pidx] = m;
            pPart[pidx + 16 * 16 * 2048] = e;
        }
    }
}

// ---------------------------------------------------------------------------
// Combine the 16 per-row-block (max, expsum) partials into per-(head, key)
// global max and 1/sum.  Grid (2048/256, NH).
// ---------------------------------------------------------------------------
__global__ __launch_bounds__(256)
void colstats(const float* __restrict__ pPart, float* __restrict__ Mg,
              float* __restrict__ iLg)
{
    const int c = blockIdx.x * 256 + threadIdx.x;
    const int h = blockIdx.y;
    const float* pm = pPart + (long long)h * 16 * 2048 + c;
    const float* pe = pm + 16 * 16 * 2048;
    float M = -1e30f;
    #pragma unroll
    for (int b = 0; b < 16; ++b) M = fmaxf(M, pm[b * 2048]);
    float Ls = 0.f;
    #pragma unroll
    for (int b = 0; b < 16; ++b) Ls += pe[b * 2048] * __expf(pm[b * 2048] - M);
    Mg[h * 2048 + c]  = M;
    iLg[h * 2048 + c] = 1.0f / Ls;
}

// ---------------------------------------------------------------------------
// fp32 -> bf16 elementwise for q,k,v (z selects input).  8 elems/thread.
// ---------------------------------------------------------------------------
__global__ __launch_bounds__(256)
void cvt_f2b3(const float* __restrict__ a, const float* __restrict__ b,
              const float* __restrict__ c, unsigned short* __restrict__ out)
{
    const float* in = blockIdx.z == 0 ? a : blockIdx.z == 1 ? b : c;
    const long long i = ((long long)blockIdx.x * 256 + threadIdx.x) * 8;
    const float4 f0 = *(const float4*)(in + i);
    const float4 f1 = *(const float4*)(in + i + 4);
    union { int4 v; unsigned short u[8]; } t;
    t.u[0] = f2bf(f0.x); t.u[1] = f2bf(f0.y); t.u[2] = f2bf(f0.z); t.u[3] = f2bf(f0.w);
    t.u[4] = f2bf(f1.x); t.u[5] = f2bf(f1.y); t.u[6] = f2bf(f1.z); t.u[7] = f2bf(f1.w);
    *(int4*)(out + (long long)blockIdx.z * 4194304 + i) = t.v;
}

// ---------------------------------------------------------------------------
// 32x32 tile transpose, fp32 in -> bf16 out. Block (32,8).
// ---------------------------------------------------------------------------
__global__ __launch_bounds__(256)
void transpose_f2b(const float* __restrict__ in, unsigned short* __restrict__ out,
                   int rows, int cols)
{
    __shared__ float t[32][33];
    const long long base = (long long)blockIdx.z * rows * cols;
    const int c0 = blockIdx.x * 32, r0 = blockIdx.y * 32;
    const int tx = threadIdx.x, ty0 = threadIdx.y;
    #pragma unroll
    for (int jj = 0; jj < 4; ++jj) {
        const int j = ty0 + jj * 8;
        t[j][tx] = in[base + (long long)(r0 + j) * cols + (c0 + tx)];
    }
    __syncthreads();
    #pragma unroll
    for (int jj = 0; jj < 4; ++jj) {
        const int j = ty0 + jj * 8;
        out[base + (long long)(c0 + j) * rows + (r0 + tx)] = f2bf(t[tx][j]);
    }
}

// Fused Wq/Wk/Wv transpose: z in [0,48), widx=z>>4 picks the weight, h=z&15.
__global__ __launch_bounds__(256)
void transpose_f2b3(const float* __restrict__ Wq, const float* __restrict__ Wk,
                    const float* __restrict__ Wv, unsigned short* __restrict__ out)
{
    __shared__ float t[32][33];
    const int z = blockIdx.z, widx = z >> 4, h = z & 15;
    const float* in = (widx == 0 ? Wq : widx == 1 ? Wk : Wv) + (long long)h * 2048 * 128;
    unsigned short* o = out + (long long)z * 262144;
    const int c0 = blockIdx.x * 32, r0 = blockIdx.y * 32;
    const int tx = threadIdx.x, ty0 = threadIdx.y;
    #pragma unroll
    for (int jj = 0; jj < 4; ++jj) {
        const int j = ty0 + jj * 8;
        t[j][tx] = in[(long long)(r0 + j) * 128 + (c0 + tx)];
    }
    __syncthreads();
    #pragma unroll
    for (int jj = 0; jj < 4; ++jj) {
        const int j = ty0 + jj * 8;
        o[(long long)(c0 + j) * 2048 + (r0 + tx)] = f2bf(t[tx][j]);
    }
}

// ---------------------------------------------------------------------------
// Residual + bias + LayerNorm (all fp32), one block (256 thr) per row of 2048.
// ---------------------------------------------------------------------------
__global__ __launch_bounds__(256)
void ln_resid(const float* __restrict__ ypre, const float* __restrict__ resid,
              const float* __restrict__ pb, const float* __restrict__ g,
              const float* __restrict__ bta, float* __restrict__ y)
{
    __shared__ float as_[4], as2_[4];
    const int l = blockIdx.x;
    const int tid = threadIdx.x;
    float v[8]; float s = 0.f, s2 = 0.f;
    #pragma unroll
    for (int i = 0; i < 8; ++i) {
        const int d = tid + i * 256;
        float t = ypre[(long long)l * DMODEL + d] + pb[d] + resid[(long long)l * DMODEL + d];
        v[i] = t; s += t; s2 += t * t;
    }
    #pragma unroll
    for (int off = 32; off > 0; off >>= 1) {
        s  += __shfl_down(s, off, 64);
        s2 += __shfl_down(s2, off, 64);
    }
    const int wave = tid >> 6, lane = tid & 63;
    if (lane == 0) { as_[wave] = s; as2_[wave] = s2; }
    __syncthreads();
    const float S  = as_[0] + as_[1] + as_[2] + as_[3];
    const float S2 = as2_[0] + as2_[1] + as2_[2] + as2_[3];
    const float mu  = S * (1.0f / DMODEL);
    const float var = S2 * (1.0f / DMODEL) - mu * mu;
    const float rs  = rsqrtf(var + 1e-5f);
    #pragma unroll
    for (int i = 0; i < 8; ++i) {
        const int d = tid + i * 256;
        y[(long long)l * DMODEL + d] = (v[i] - mu) * rs * g[d] + bta[d];
    }
}

// ---------------------------------------------------------------------------
extern "C" void kernel_launch(void* const* d_in, const int* in_sizes, int n_in,
                              void* d_out, int out_size, void* d_ws, size_t ws_size,
                              hipStream_t stream)
{
    const float* q  = (const float*)d_in[0];
    const float* k  = (const float*)d_in[1];
    const float* v  = (const float*)d_in[2];
    const float* Wq = (const float*)d_in[3];
    const float* Wk = (const float*)d_in[4];
    const float* Wv = (const float*)d_in[5];
    const float* Pw = (const float*)d_in[6];
    const float* Pb = (const float*)d_in[7];
    const float* Lg = (const float*)d_in[8];
    const float* Lb = (const float*)d_in[9];

    float* y    = (float*)d_out;
    float* attn = y + (size_t)L * DMODEL;               // output 1 (fp32), 268 MB

    // ws layout (bf16 elems), 40 MB:
    //   T0 [0,8MB): softmax stats (pPart 4MB + Mg/iLg 256KB) during attention,
    //               then Pw^T (8MB) for the proj GEMM (strictly after PV).
    //   qh [8,16), kh [16,24), vhT [24,32), O [32,40)
    //   ypre fp32 overlays qh+kh (dead after the scores GEMM).
    // attn output region (268MB) is dead until the scores GEMM writes it, so
    // bf16 q,k,v (24MB) + Wq/Wk/Wv^T (24MB) are stashed there first.
    const size_t SEG = (size_t)4194304;
    unsigned short* T0  = (unsigned short*)d_ws;
    unsigned short* qh  = T0 + SEG;
    unsigned short* kh  = qh + SEG;
    unsigned short* vhT = kh + SEG;
    unsigned short* O   = vhT + SEG;
    float* ypre  = (float*)qh;
    float* pPart = (float*)d_ws;                        // [2][16][16][2048] fp32 = 4MB
    float* Mg    = pPart + 2 * 16 * 16 * 2048;          // [16][2048]
    float* iLg   = Mg + 16 * 2048;

    unsigned short* qkvb = (unsigned short*)attn;       // qb,kb,vb: 3 x SEG
    unsigned short* WT   = qkvb + 3 * SEG;              // WqT,WkT,WvT: 48 x 262144

    const float inv_temper = 0.022097086912079608f;     // 1/sqrt(2048)
    dim3 tb(32, 8);

    // Stage 0: bf16-ify q,k,v; transpose all three weights.
    cvt_f2b3<<<dim3(2048, 1, 3), 256, 0, stream>>>(q, k, v, qkvb);
    transpose_f2b3<<<dim3(4, 64, 48), tb, 0, stream>>>(Wq, Wk, Wv, WT);

    // Stage 1: fused Q/K/V projections, z = 48 (3 x 16 heads).
    gemm_bt<3, 0, 64, 0><<<dim3(1, 32, 48), 256, 0, stream>>>(qkvb, WT, qh,
        2048, 128, 2048, 2048, 2048, 0, 4194304LL, 262144LL, 262144LL, inv_temper,
        nullptr, nullptr, nullptr, nullptr);

    // Stage 2: logits[h] = qh[h] @ kh[h]^T -> fp32 attn region, plus
    // per-block column (max, expsum) partials for the query-axis softmax.
    gemm_bt<2, 0, 128, 1><<<dim3(16, 16, 16), 256, 0, stream>>>(qh, kh, attn,
        2048, 2048, 128, 128, 128, 2048, 262144LL, 262144LL, 4194304LL, 1.0f,
        nullptr, nullptr, nullptr, pPart);

    // Stage 3: reduce partials -> per-(head,key) global max & 1/sum.
    colstats<<<dim3(8, NH), 256, 0, stream>>>(pPart, Mg, iLg);

    // Stage 4: PV.  A-staging normalizes logits -> attn fp32 (written back in
    // place, exactly once per element) and feeds bf16(p) to the MFMA.
    gemm_bt<0, 2, 64, 0><<<dim3(1, 32, 16), 256, 0, stream>>>(attn, vhT, O,
        2048, 128, 2048, 2048, 2048, 2048, 4194304LL, 262144LL, 128LL, 1.0f,
        Mg, iLg, attn, nullptr);

    // Stage 5: ypre = O @ proj_w  (fp32 out, M=N=K=2048)
    transpose_f2b<<<dim3(64, 64, 1), tb, 0, stream>>>(Pw, T0, 2048, 2048);
    gemm_bt<2, 0, 64, 0><<<dim3(16, 32, 1), 256, 0, stream>>>(O, T0, (void*)ypre,
        2048, 2048, 2048, 2048, 2048, 2048, 0LL, 0LL, 0LL, 1.0f,
        nullptr, nullptr, nullptr, nullptr);

    // Stage 6: y = LayerNorm(ypre + proj_b + residual) * g + b
    ln_resid<<<dim3(2048), 256, 0, stream>>>(ypre, q, Pb, Lg, Lb, y);
}

// Round 5
// 639.354 us; speedup vs baseline: 1.4526x; 1.0958x over previous
//
#include <hip/hip_runtime.h>
#include <stdint.h>

#define L 2048
#define DMODEL 2048
#define NH 16

typedef __bf16 bf16x8 __attribute__((ext_vector_type(8)));
typedef float f32x4 __attribute__((ext_vector_type(4)));
typedef short s16x4 __attribute__((ext_vector_type(4)));

__device__ __forceinline__ unsigned short f2bf(float f) {
    union { float f; unsigned int i; } w; w.f = f;
    unsigned int u = w.i;
    unsigned int r = u + 0x7fffu + ((u >> 16) & 1u);
    return (unsigned short)(r >> 16);
}

// Async global->LDS, 16 bytes per lane.  LDS dest is wave-uniform base +
// lane*16 (m104) -- thread tid writes LDS offset tid*16B, contiguous.
__device__ __forceinline__ void gload_lds16(const unsigned short* g, unsigned short* l) {
    __builtin_amdgcn_global_load_lds(
        (const __attribute__((address_space(1))) void*)g,
        (__attribute__((address_space(3))) void*)l, 16, 0, 0);
}

// ---------------------------------------------------------------------------
// Tiled bf16-MFMA GEMM, C = alpha * A (MxK) * B'(NxK)^T.  B' is B transposed
// (row n of B' holds column n of B, contiguous in K), always bf16, staged via
// global_load_lds.  Double-buffered LDS, ONE __syncthreads per K-step: stage
// of tile t+1 is issued before compute of tile t (2-phase pipeline; barrier
// keeps full-drain semantics so this is race-free code motion).
// AMODE 0: A bf16, global_load_lds staging.
// AMODE 2: A fp32 logits; staging applies column-softmax normalize
//          p = exp(s - Mg[col]) * iLg[col], writes p back to Awr IN PLACE
//          (each element staged exactly once: gridDim.x==1), feeds bf16(p)
//          to MFMA.  Requires BM=64.
// CMODE 0: C bf16 row-major [m][n]   (ldc = row stride)
// CMODE 1: C bf16 transposed [n][m]
// CMODE 2: C fp32 row-major [m][n]
// CMODE 3: fused QKV: z<32 -> mode0 (ldc=128, alpha for z<16), z>=32 ->
//          mode1 (ldc=2048).  A base advances by sA per z>>4.
// PSM 1 (CMODE 2, BM=128 only): epilogue emits per-block column-softmax
//   partials: pPart[(z*16+by)*2048+col] = max, [+16*16*2048] = sum exp(s-max).
// BM tile rows (64/128), BK K-step (32/64).  Per-step MFMA/wave =
// (BM/32)*4*(BK/32); barriers = K/BK.
// Grid (N/128, M/BM, batch), block 256 (4 waves).
// ---------------------------------------------------------------------------
template<int CMODE, int AMODE, int BM, int BK, int PSM>
__global__ __launch_bounds__(256, 2)
void gemm_bt(const void* Av,
             const unsigned short* __restrict__ B,
             void* __restrict__ C,
             int M, int N, int K, int lda, int ldb, int ldc,
             long long sA, long long sB, long long sC, float alpha,
             const float* __restrict__ Mg, const float* __restrict__ iLg,
             float* Awr, float* __restrict__ pPart)
{
    static_assert(AMODE != 2 || BM == 64, "softmax-A path assumes BM==64");
    static_assert(PSM == 0 || BM == 128, "PSM partials assume BM==128");
    constexpr int KC8 = BK / 8;            // 16B chunks per row
    constexpr int CA  = BM * BK / 2048;    // A chunks per thread
    constexpr int CB  = BK / 16;           // B chunks per thread (BN=128)
    constexpr int MFR = BM / 32;           // m-fragments per wave
    constexpr int KG  = BK / 32;           // MFMA K-groups per step

    __shared__ unsigned short As[2][BM * BK];
    __shared__ unsigned short Bs[2][128 * BK];

    const int tid  = threadIdx.x;
    const int wave = tid >> 6;
    const int lane = tid & 63;
    const int quad = lane >> 4;
    const int l16  = lane & 15;

    const int tileN = blockIdx.x * 128;
    const int tileM = blockIdx.y * BM;

    const long long zA = (CMODE == 3) ? (long long)(blockIdx.z >> 4) : (long long)blockIdx.z;
    const unsigned short* A16 = (const unsigned short*)Av + zA * sA;
    const float*          A32 = (const float*)Av + zA * sA;
    B += (long long)blockIdx.z * sB;

    const int wm = (wave >> 1) * (BM / 2);
    const int wn = (wave & 1) * 64;

    // -------- staging helpers --------
    float4 fa[CA > 0 ? CA : 1][2];         // AMODE2 in-flight A values
    float4 m0, m1, l0, l1;                 // AMODE2 stats (k-shared across chunks)
    long long aoff[CA > 0 ? CA : 1];

    auto stageB = [&](int kk, int buf) {
        #pragma unroll
        for (int j = 0; j < CB; ++j) {
            const int ch = tid + j * 256;
            const int rb = ch / KC8, kb = (ch % KC8) * 8;
            gload_lds16(B + (long long)(tileN + rb) * ldb + (kk + kb), &Bs[buf][ch * 8]);
        }
    };
    auto stageA_gl = [&](int kk, int buf) {
        #pragma unroll
        for (int j = 0; j < CA; ++j) {
            const int ch = tid + j * 256;
            const int ra = ch / KC8, ka = (ch % KC8) * 8;
            gload_lds16(A16 + (long long)(tileM + ra) * lda + (kk + ka), &As[buf][ch * 8]);
        }
    };
    auto loadA_sm = [&](int kk) {       // issue loads (early)
        #pragma unroll
        for (int j = 0; j < CA; ++j) {
            const int ch = tid + j * 256;
            const int ra = ch / KC8, ka = (ch % KC8) * 8;
            aoff[j] = (long long)(tileM + ra) * lda + (kk + ka);
            const float* p = A32 + aoff[j];
            fa[j][0] = *(const float4*)p;  fa[j][1] = *(const float4*)(p + 4);
        }
        const int ka = (tid % KC8) * 8;   // 256%KC8==0 -> k-offset shared by chunks
        const long long sb = (long long)blockIdx.z * 2048 + (kk + ka);
        m0 = *(const float4*)(Mg + sb);  m1 = *(const float4*)(Mg + sb + 4);
        l0 = *(const float4*)(iLg + sb); l1 = *(const float4*)(iLg + sb + 4);
    };
    auto finA_sm = [&](int buf) {       // normalize + writeback + LDS (late)
        #pragma unroll
        for (int j = 0; j < CA; ++j) {
            float4 g0 = fa[j][0], g1 = fa[j][1];
            g0.x = __expf(g0.x - m0.x) * l0.x;  g0.y = __expf(g0.y - m0.y) * l0.y;
            g0.z = __expf(g0.z - m0.z) * l0.z;  g0.w = __expf(g0.w - m0.w) * l0.w;
            g1.x = __expf(g1.x - m1.x) * l1.x;  g1.y = __expf(g1.y - m1.y) * l1.y;
            g1.z = __expf(g1.z - m1.z) * l1.z;  g1.w = __expf(g1.w - m1.w) * l1.w;
            float* wb = Awr + (long long)blockIdx.z * sA + aoff[j];
            *(float4*)wb = g0;  *(float4*)(wb + 4) = g1;
            union { int4 v; unsigned short u[8]; } tt;
            tt.u[0] = f2bf(g0.x); tt.u[1] = f2bf(g0.y); tt.u[2] = f2bf(g0.z); tt.u[3] = f2bf(g0.w);
            tt.u[4] = f2bf(g1.x); tt.u[5] = f2bf(g1.y); tt.u[6] = f2bf(g1.z); tt.u[7] = f2bf(g1.w);
            *(int4*)(&As[buf][(tid + j * 256) * 8]) = tt.v;
        }
    };

    f32x4 acc[MFR][4] = {};
    const int nt = K / BK;

    // -------- prologue: stage tile 0 into buffer 0 --------
    if constexpr (AMODE == 0) {
        stageA_gl(0, 0);
    } else {
        loadA_sm(0);
        finA_sm(0);
    }
    stageB(0, 0);
    __syncthreads();

    int cur = 0;
    for (int t = 0; t < nt; ++t) {
        const int nxt = cur ^ 1;
        const int k0n = (t + 1) * BK;
        const bool pf = (t + 1 < nt);

        // issue next-tile staging BEFORE compute (latency hides under MFMA)
        if (pf) {
            if constexpr (AMODE == 0) stageA_gl(k0n, nxt);
            else                      loadA_sm(k0n);
            stageB(k0n, nxt);
        }

        // compute current tile
        bf16x8 af[MFR][KG], bfr[4][KG];
        #pragma unroll
        for (int i = 0; i < MFR; ++i)
            #pragma unroll
            for (int g = 0; g < KG; ++g)
                af[i][g] = *(const bf16x8*)(&As[cur][(wm + i * 16 + l16) * BK + g * 32 + quad * 8]);
        #pragma unroll
        for (int j = 0; j < 4; ++j)
            #pragma unroll
            for (int g = 0; g < KG; ++g)
                bfr[j][g] = *(const bf16x8*)(&Bs[cur][(wn + j * 16 + l16) * BK + g * 32 + quad * 8]);
        #pragma unroll
        for (int g = 0; g < KG; ++g)
            #pragma unroll
            for (int i = 0; i < MFR; ++i)
                #pragma unroll
                for (int j = 0; j < 4; ++j)
                    acc[i][j] = __builtin_amdgcn_mfma_f32_16x16x32_bf16(af[i][g], bfr[j][g], acc[i][j], 0, 0, 0);

        if constexpr (AMODE == 2) { if (pf) finA_sm(nxt); }

        __syncthreads();             // drains vmcnt+lgkm: next staged, cur reads done
        cur = nxt;
    }

    // -------- epilogue.  D layout: col = lane&15, row = quad*4+reg [m89] ----
    const long long cb = (long long)blockIdx.z * sC;
    const float aEff = (CMODE == 3) ? (blockIdx.z < 16 ? alpha : 1.0f) : alpha;
    #pragma unroll
    for (int i = 0; i < MFR; ++i) {
        const int r0 = tileM + wm + i * 16 + quad * 4;
        #pragma unroll
        for (int j = 0; j < 4; ++j) {
            const int c = tileN + wn + j * 16 + l16;
            f32x4 d = acc[i][j];
            if (CMODE == 0) {
                unsigned short* Cp = (unsigned short*)C + cb;
                #pragma unroll
                for (int r = 0; r < 4; ++r)
                    Cp[(long long)(r0 + r) * ldc + c] = f2bf(d[r] * aEff);
            } else if (CMODE == 1) {
                unsigned short* Cp = (unsigned short*)C + cb + (long long)c * ldc + r0;
                s16x4 pk;
                #pragma unroll
                for (int r = 0; r < 4; ++r) pk[r] = (short)f2bf(d[r] * aEff);
                *(s16x4*)Cp = pk;
            } else if (CMODE == 2) {
                float* Cp = (float*)C + cb;
                #pragma unroll
                for (int r = 0; r < 4; ++r)
                    Cp[(long long)(r0 + r) * ldc + c] = d[r] * aEff;
            } else { // CMODE 3: fused QKV
                if (blockIdx.z < 32) {          // qh/kh, bf16 row-major, ldc=128
                    unsigned short* Cp = (unsigned short*)C + cb;
                    #pragma unroll
                    for (int r = 0; r < 4; ++r)
                        Cp[(long long)(r0 + r) * 128 + c] = f2bf(d[r] * aEff);
                } else {                         // vhT, bf16 transposed, ldc=2048
                    unsigned short* Cp = (unsigned short*)C + cb + (long long)c * 2048 + r0;
                    s16x4 pk;
                    #pragma unroll
                    for (int r = 0; r < 4; ++r) pk[r] = (short)f2bf(d[r]);
                    *(s16x4*)Cp = pk;
                }
            }
        }
    }

    // -------- column-softmax partials (query-axis SM, alpha==1 here) --------
    if constexpr (PSM) {
        __shared__ float shPm[2][128], shPe[2][128];
        const int wmh = wave >> 1;
        #pragma unroll
        for (int j = 0; j < 4; ++j) {
            float mj = -1e30f;
            #pragma unroll
            for (int i = 0; i < MFR; ++i)
                #pragma unroll
                for (int r = 0; r < 4; ++r) mj = fmaxf(mj, acc[i][j][r]);
            float ej = 0.f;
            #pragma unroll
            for (int i = 0; i < MFR; ++i)
                #pragma unroll
                for (int r = 0; r < 4; ++r) ej += __expf(acc[i][j][r] - mj);
            #pragma unroll
            for (int off = 16; off < 64; off <<= 1) {   // reduce across quads
                float mo = __shfl_xor(mj, off, 64);
                float eo = __shfl_xor(ej, off, 64);
                float mn = fmaxf(mj, mo);
                ej = ej * __expf(mj - mn) + eo * __expf(mo - mn);
                mj = mn;
            }
            if (quad == 0) {
                shPm[wmh][wn + j * 16 + l16] = mj;
                shPe[wmh][wn + j * 16 + l16] = ej;
            }
        }
        __syncthreads();
        if (tid < 128) {
            const float mA = shPm[0][tid], mB = shPm[1][tid];
            const float m = fmaxf(mA, mB);
            const float e = shPe[0][tid] * __expf(mA - m) + shPe[1][tid] * __expf(mB - m);
            const long long pidx = ((long long)blockIdx.z * 16 + blockIdx.y) * 2048 + tileN + tid;
            pPart[pidx] = m;
            pPart[pidx + 16 * 16 * 2048] = e;
        }
    }
}

// ---------------------------------------------------------------------------
// Combine the 16 per-row-block (max, expsum) partials into per-(head, key)
// global max and 1/sum.  Grid (2048/256, NH).
// ---------------------------------------------------------------------------
__global__ __launch_bounds__(256)
void colstats(const float* __restrict__ pPart, float* __restrict__ Mg,
              float* __restrict__ iLg)
{
    const int c = blockIdx.x * 256 + threadIdx.x;
    const int h = blockIdx.y;
    const float* pm = pPart + (long long)h * 16 * 2048 + c;
    const float* pe = pm + 16 * 16 * 2048;
    float M = -1e30f;
    #pragma unroll
    for (int b = 0; b < 16; ++b) M = fmaxf(M, pm[b * 2048]);
    float Ls = 0.f;
    #pragma unroll
    for (int b = 0; b < 16; ++b) Ls += pe[b * 2048] * __expf(pm[b * 2048] - M);
    Mg[h * 2048 + c]  = M;
    iLg[h * 2048 + c] = 1.0f / Ls;
}

// ---------------------------------------------------------------------------
// fp32 -> bf16 elementwise for q,k,v (z selects input).  8 elems/thread.
// ---------------------------------------------------------------------------
__global__ __launch_bounds__(256)
void cvt_f2b3(const float* __restrict__ a, const float* __restrict__ b,
              const float* __restrict__ c, unsigned short* __restrict__ out)
{
    const float* in = blockIdx.z == 0 ? a : blockIdx.z == 1 ? b : c;
    const long long i = ((long long)blockIdx.x * 256 + threadIdx.x) * 8;
    const float4 f0 = *(const float4*)(in + i);
    const float4 f1 = *(const float4*)(in + i + 4);
    union { int4 v; unsigned short u[8]; } t;
    t.u[0] = f2bf(f0.x); t.u[1] = f2bf(f0.y); t.u[2] = f2bf(f0.z); t.u[3] = f2bf(f0.w);
    t.u[4] = f2bf(f1.x); t.u[5] = f2bf(f1.y); t.u[6] = f2bf(f1.z); t.u[7] = f2bf(f1.w);
    *(int4*)(out + (long long)blockIdx.z * 4194304 + i) = t.v;
}

// ---------------------------------------------------------------------------
// 32x32 tile transpose, fp32 in -> bf16 out. Block (32,8).
// ---------------------------------------------------------------------------
__global__ __launch_bounds__(256)
void transpose_f2b(const float* __restrict__ in, unsigned short* __restrict__ out,
                   int rows, int cols)
{
    __shared__ float t[32][33];
    const long long base = (long long)blockIdx.z * rows * cols;
    const int c0 = blockIdx.x * 32, r0 = blockIdx.y * 32;
    const int tx = threadIdx.x, ty0 = threadIdx.y;
    #pragma unroll
    for (int jj = 0; jj < 4; ++jj) {
        const int j = ty0 + jj * 8;
        t[j][tx] = in[base + (long long)(r0 + j) * cols + (c0 + tx)];
    }
    __syncthreads();
    #pragma unroll
    for (int jj = 0; jj < 4; ++jj) {
        const int j = ty0 + jj * 8;
        out[base + (long long)(c0 + j) * rows + (r0 + tx)] = f2bf(t[tx][j]);
    }
}

// Fused Wq/Wk/Wv transpose: z in [0,48), widx=z>>4 picks the weight, h=z&15.
__global__ __launch_bounds__(256)
void transpose_f2b3(const float* __restrict__ Wq, const float* __restrict__ Wk,
                    const float* __restrict__ Wv, unsigned short* __restrict__ out)
{
    __shared__ float t[32][33];
    const int z = blockIdx.z, widx = z >> 4, h = z & 15;
    const float* in = (widx == 0 ? Wq : widx == 1 ? Wk : Wv) + (long long)h * 2048 * 128;
    unsigned short* o = out + (long long)z * 262144;
    const int c0 = blockIdx.x * 32, r0 = blockIdx.y * 32;
    const int tx = threadIdx.x, ty0 = threadIdx.y;
    #pragma unroll
    for (int jj = 0; jj < 4; ++jj) {
        const int j = ty0 + jj * 8;
        t[j][tx] = in[(long long)(r0 + j) * 128 + (c0 + tx)];
    }
    __syncthreads();
    #pragma unroll
    for (int jj = 0; jj < 4; ++jj) {
        const int j = ty0 + jj * 8;
        o[(long long)(c0 + j) * 2048 + (r0 + tx)] = f2bf(t[tx][j]);
    }
}

// ---------------------------------------------------------------------------
// Residual + bias + LayerNorm (all fp32), one block (256 thr) per row of 2048.
// ---------------------------------------------------------------------------
__global__ __launch_bounds__(256)
void ln_resid(const float* __restrict__ ypre, const float* __restrict__ resid,
              const float* __restrict__ pb, const float* __restrict__ g,
              const float* __restrict__ bta, float* __restrict__ y)
{
    __shared__ float as_[4], as2_[4];
    const int l = blockIdx.x;
    const int tid = threadIdx.x;
    float v[8]; float s = 0.f, s2 = 0.f;
    #pragma unroll
    for (int i = 0; i < 8; ++i) {
        const int d = tid + i * 256;
        float t = ypre[(long long)l * DMODEL + d] + pb[d] + resid[(long long)l * DMODEL + d];
        v[i] = t; s += t; s2 += t * t;
    }
    #pragma unroll
    for (int off = 32; off > 0; off >>= 1) {
        s  += __shfl_down(s, off, 64);
        s2 += __shfl_down(s2, off, 64);
    }
    const int wave = tid >> 6, lane = tid & 63;
    if (lane == 0) { as_[wave] = s; as2_[wave] = s2; }
    __syncthreads();
    const float S  = as_[0] + as_[1] + as_[2] + as_[3];
    const float S2 = as2_[0] + as2_[1] + as2_[2] + as2_[3];
    const float mu  = S * (1.0f / DMODEL);
    const float var = S2 * (1.0f / DMODEL) - mu * mu;
    const float rs  = rsqrtf(var + 1e-5f);
    #pragma unroll
    for (int i = 0; i < 8; ++i) {
        const int d = tid + i * 256;
        y[(long long)l * DMODEL + d] = (v[i] - mu) * rs * g[d] + bta[d];
    }
}

// ---------------------------------------------------------------------------
extern "C" void kernel_launch(void* const* d_in, const int* in_sizes, int n_in,
                              void* d_out, int out_size, void* d_ws, size_t ws_size,
                              hipStream_t stream)
{
    const float* q  = (const float*)d_in[0];
    const float* k  = (const float*)d_in[1];
    const float* v  = (const float*)d_in[2];
    const float* Wq = (const float*)d_in[3];
    const float* Wk = (const float*)d_in[4];
    const float* Wv = (const float*)d_in[5];
    const float* Pw = (const float*)d_in[6];
    const float* Pb = (const float*)d_in[7];
    const float* Lg = (const float*)d_in[8];
    const float* Lb = (const float*)d_in[9];

    float* y    = (float*)d_out;
    float* attn = y + (size_t)L * DMODEL;               // output 1 (fp32), 268 MB

    // ws layout (bf16 elems), 40 MB:
    //   T0 [0,8MB): softmax stats (pPart 4MB + Mg/iLg 256KB) during attention,
    //               then Pw^T (8MB) for the proj GEMM (strictly after PV).
    //   qh [8,16), kh [16,24), vhT [24,32), O [32,40)
    //   ypre fp32 overlays qh+kh (dead after the scores GEMM).
    // attn output region (268MB) is dead until the scores GEMM writes it, so
    // bf16 q,k,v (24MB) + Wq/Wk/Wv^T (24MB) are stashed there first.
    const size_t SEG = (size_t)4194304;
    unsigned short* T0  = (unsigned short*)d_ws;
    unsigned short* qh  = T0 + SEG;
    unsigned short* kh  = qh + SEG;
    unsigned short* vhT = kh + SEG;
    unsigned short* O   = vhT + SEG;
    float* ypre  = (float*)qh;
    float* pPart = (float*)d_ws;                        // [2][16][16][2048] fp32 = 4MB
    float* Mg    = pPart + 2 * 16 * 16 * 2048;          // [16][2048]
    float* iLg   = Mg + 16 * 2048;

    unsigned short* qkvb = (unsigned short*)attn;       // qb,kb,vb: 3 x SEG
    unsigned short* WT   = qkvb + 3 * SEG;              // WqT,WkT,WvT: 48 x 262144

    const float inv_temper = 0.022097086912079608f;     // 1/sqrt(2048)
    dim3 tb(32, 8);

    // Stage 0: bf16-ify q,k,v; transpose all three weights.
    cvt_f2b3<<<dim3(2048, 1, 3), 256, 0, stream>>>(q, k, v, qkvb);
    transpose_f2b3<<<dim3(4, 64, 48), tb, 0, stream>>>(Wq, Wk, Wv, WT);

    // Stage 1: fused Q/K/V projections, z = 48 (3 x 16 heads).
    // BM=128 -> 768 blocks (3/CU) with 16 MFMA per barrier.
    gemm_bt<3, 0, 128, 32, 0><<<dim3(1, 16, 48), 256, 0, stream>>>(qkvb, WT, qh,
        2048, 128, 2048, 2048, 2048, 0, 4194304LL, 262144LL, 262144LL, inv_temper,
        nullptr, nullptr, nullptr, nullptr);

    // Stage 2: logits[h] = qh[h] @ kh[h]^T -> fp32 attn region, plus
    // per-block column (max, expsum) partials for the query-axis softmax.
    gemm_bt<2, 0, 128, 32, 1><<<dim3(16, 16, 16), 256, 0, stream>>>(qh, kh, attn,
        2048, 2048, 128, 128, 128, 2048, 262144LL, 262144LL, 4194304LL, 1.0f,
        nullptr, nullptr, nullptr, pPart);

    // Stage 3: reduce partials -> per-(head,key) global max & 1/sum.
    colstats<<<dim3(8, NH), 256, 0, stream>>>(pPart, Mg, iLg);

    // Stage 4: PV.  A-staging normalizes logits -> attn fp32 (written back in
    // place, exactly once per element) and feeds bf16(p) to the MFMA.
    // BK=64: 32 barriers instead of 64, 16 MFMA per barrier.
    gemm_bt<0, 2, 64, 64, 0><<<dim3(1, 32, 16), 256, 0, stream>>>(attn, vhT, O,
        2048, 128, 2048, 2048, 2048, 2048, 4194304LL, 262144LL, 128LL, 1.0f,
        Mg, iLg, attn, nullptr);

    // Stage 5: ypre = O @ proj_w  (fp32 out, M=N=K=2048), BK=64.
    transpose_f2b<<<dim3(64, 64, 1), tb, 0, stream>>>(Pw, T0, 2048, 2048);
    gemm_bt<2, 0, 64, 64, 0><<<dim3(16, 32, 1), 256, 0, stream>>>(O, T0, (void*)ypre,
        2048, 2048, 2048, 2048, 2048, 2048, 0LL, 0LL, 0LL, 1.0f,
        nullptr, nullptr, nullptr, nullptr);

    // Stage 6: y = LayerNorm(ypre + proj_b + residual) * g + b
    ln_resid<<<dim3(2048), 256, 0, stream>>>(ypre, q, Pb, Lg, Lb, y);
}

// Round 6
// 596.727 us; speedup vs baseline: 1.5564x; 1.0714x over previous
//
#include <hip/hip_runtime.h>
#include <stdint.h>

#define L 2048
#define DMODEL 2048
#define NH 16

typedef __bf16 bf16x8 __attribute__((ext_vector_type(8)));
typedef float f32x4 __attribute__((ext_vector_type(4)));
typedef short s16x4 __attribute__((ext_vector_type(4)));

__device__ __forceinline__ unsigned short f2bf(float f) {
    union { float f; unsigned int i; } w; w.f = f;
    unsigned int u = w.i;
    unsigned int r = u + 0x7fffu + ((u >> 16) & 1u);
    return (unsigned short)(r >> 16);
}

// Async global->LDS, 16 bytes per lane.  LDS dest is wave-uniform base +
// lane*16 (m104); swizzled layouts are achieved by pre-swizzling the GLOBAL
// source address (rule 21: both-sides involution).
__device__ __forceinline__ void gload_lds16(const unsigned short* g, unsigned short* l) {
    __builtin_amdgcn_global_load_lds(
        (const __attribute__((address_space(1))) void*)g,
        (__attribute__((address_space(3))) void*)l, 16, 0, 0);
}

// ---------------------------------------------------------------------------
// Tiled bf16-MFMA GEMM, C = alpha * A (MxK) * B'(NxK)^T.  A,B bf16, staged via
// global_load_lds.  Double-buffered LDS, one __syncthreads per K-step: stage
// of tile t+1 issued before compute of tile t.
// CMODE 0: C bf16 row-major [m][n]      CMODE 1: C bf16 transposed [n][m]
// CMODE 2: C fp32 row-major [m][n]      CMODE 4: NO C write (stats only)
// CMODE 3: fused QKV: z<32 -> mode0 (ldc=128, alpha for z<16), z>=32 ->
//          mode1 (ldc=2048).  A base advances by sA per z>>4.
// PSM 1 (BM=128): epilogue emits per-block column-softmax partials:
//   pPart[(z*16+by)*2048+col] = max, [+16*16*2048] = sum exp(s-max).
// Grid (N/128, M/BM, batch), block 256 (4 waves).
// ---------------------------------------------------------------------------
template<int CMODE, int BM, int BK, int PSM>
__global__ __launch_bounds__(256, 2)
void gemm_bt(const unsigned short* __restrict__ Ag,
             const unsigned short* __restrict__ B,
             void* __restrict__ C,
             int K, int lda, int ldb, int ldc,
             long long sA, long long sB, long long sC, float alpha,
             float* __restrict__ pPart)
{
    constexpr int KC8 = BK / 8;            // 16B chunks per row
    constexpr int CA  = BM * BK / 2048;    // A chunks per thread
    constexpr int CB  = BK / 16;           // B chunks per thread (BN=128)
    constexpr int MFR = BM / 32;           // m-fragments per wave
    constexpr int KG  = BK / 32;           // MFMA K-groups per step

    __shared__ unsigned short As[2][BM * BK];
    __shared__ unsigned short Bs[2][128 * BK];

    const int tid  = threadIdx.x;
    const int wave = tid >> 6;
    const int lane = tid & 63;
    const int quad = lane >> 4;
    const int l16  = lane & 15;

    const int tileN = blockIdx.x * 128;
    const int tileM = blockIdx.y * BM;

    const long long zA = (CMODE == 3) ? (long long)(blockIdx.z >> 4) : (long long)blockIdx.z;
    const unsigned short* A16 = Ag + zA * sA;
    B += (long long)blockIdx.z * sB;

    const int wm = (wave >> 1) * (BM / 2);
    const int wn = (wave & 1) * 64;

    auto stageB = [&](int kk, int buf) {
        #pragma unroll
        for (int j = 0; j < CB; ++j) {
            const int ch = tid + j * 256;
            const int rb = ch / KC8, kb = (ch % KC8) * 8;
            gload_lds16(B + (long long)(tileN + rb) * ldb + (kk + kb), &Bs[buf][ch * 8]);
        }
    };
    auto stageA = [&](int kk, int buf) {
        #pragma unroll
        for (int j = 0; j < CA; ++j) {
            const int ch = tid + j * 256;
            const int ra = ch / KC8, ka = (ch % KC8) * 8;
            gload_lds16(A16 + (long long)(tileM + ra) * lda + (kk + ka), &As[buf][ch * 8]);
        }
    };

    f32x4 acc[MFR][4] = {};
    const int nt = K / BK;

    stageA(0, 0);
    stageB(0, 0);
    __syncthreads();

    int cur = 0;
    for (int t = 0; t < nt; ++t) {
        const int nxt = cur ^ 1;
        const int k0n = (t + 1) * BK;
        if (t + 1 < nt) { stageA(k0n, nxt); stageB(k0n, nxt); }

        bf16x8 af[MFR][KG], bfr[4][KG];
        #pragma unroll
        for (int i = 0; i < MFR; ++i)
            #pragma unroll
            for (int g = 0; g < KG; ++g)
                af[i][g] = *(const bf16x8*)(&As[cur][(wm + i * 16 + l16) * BK + g * 32 + quad * 8]);
        #pragma unroll
        for (int j = 0; j < 4; ++j)
            #pragma unroll
            for (int g = 0; g < KG; ++g)
                bfr[j][g] = *(const bf16x8*)(&Bs[cur][(wn + j * 16 + l16) * BK + g * 32 + quad * 8]);
        #pragma unroll
        for (int g = 0; g < KG; ++g)
            #pragma unroll
            for (int i = 0; i < MFR; ++i)
                #pragma unroll
                for (int j = 0; j < 4; ++j)
                    acc[i][j] = __builtin_amdgcn_mfma_f32_16x16x32_bf16(af[i][g], bfr[j][g], acc[i][j], 0, 0, 0);

        __syncthreads();
        cur = nxt;
    }

    // Epilogue.  D layout: col = lane&15, row = quad*4+reg  [m89-verified]
    const long long cb = (long long)blockIdx.z * sC;
    const float aEff = (CMODE == 3) ? (blockIdx.z < 16 ? alpha : 1.0f) : alpha;
    if constexpr (CMODE != 4) {
        #pragma unroll
        for (int i = 0; i < MFR; ++i) {
            const int r0 = tileM + wm + i * 16 + quad * 4;
            #pragma unroll
            for (int j = 0; j < 4; ++j) {
                const int c = tileN + wn + j * 16 + l16;
                f32x4 d = acc[i][j];
                if (CMODE == 0) {
                    unsigned short* Cp = (unsigned short*)C + cb;
                    #pragma unroll
                    for (int r = 0; r < 4; ++r)
                        Cp[(long long)(r0 + r) * ldc + c] = f2bf(d[r] * aEff);
                } else if (CMODE == 1) {
                    unsigned short* Cp = (unsigned short*)C + cb + (long long)c * ldc + r0;
                    s16x4 pk;
                    #pragma unroll
                    for (int r = 0; r < 4; ++r) pk[r] = (short)f2bf(d[r] * aEff);
                    *(s16x4*)Cp = pk;
                } else if (CMODE == 2) {
                    float* Cp = (float*)C + cb;
                    #pragma unroll
                    for (int r = 0; r < 4; ++r)
                        Cp[(long long)(r0 + r) * ldc + c] = d[r] * aEff;
                } else { // CMODE 3: fused QKV
                    if (blockIdx.z < 32) {          // qh/kh, bf16 row-major, ldc=128
                        unsigned short* Cp = (unsigned short*)C + cb;
                        #pragma unroll
                        for (int r = 0; r < 4; ++r)
                            Cp[(long long)(r0 + r) * 128 + c] = f2bf(d[r] * aEff);
                    } else {                         // vhT, bf16 transposed, ldc=2048
                        unsigned short* Cp = (unsigned short*)C + cb + (long long)c * 2048 + r0;
                        s16x4 pk;
                        #pragma unroll
                        for (int r = 0; r < 4; ++r) pk[r] = (short)f2bf(d[r]);
                        *(s16x4*)Cp = pk;
                    }
                }
            }
        }
    }

    // Column-softmax partials (query-axis SM)
    if constexpr (PSM) {
        __shared__ float shPm[2][128], shPe[2][128];
        const int wmh = wave >> 1;
        #pragma unroll
        for (int j = 0; j < 4; ++j) {
            float mj = -1e30f;
            #pragma unroll
            for (int i = 0; i < MFR; ++i)
                #pragma unroll
                for (int r = 0; r < 4; ++r) mj = fmaxf(mj, acc[i][j][r]);
            float ej = 0.f;
            #pragma unroll
            for (int i = 0; i < MFR; ++i)
                #pragma unroll
                for (int r = 0; r < 4; ++r) ej += __expf(acc[i][j][r] - mj);
            #pragma unroll
            for (int off = 16; off < 64; off <<= 1) {   // reduce across quads
                float mo = __shfl_xor(mj, off, 64);
                float eo = __shfl_xor(ej, off, 64);
                float mn = fmaxf(mj, mo);
                ej = ej * __expf(mj - mn) + eo * __expf(mo - mn);
                mj = mn;
            }
            if (quad == 0) {
                shPm[wmh][wn + j * 16 + l16] = mj;
                shPe[wmh][wn + j * 16 + l16] = ej;
            }
        }
        __syncthreads();
        if (tid < 128) {
            const float mA = shPm[0][tid], mB = shPm[1][tid];
            const float m = fmaxf(mA, mB);
            const float e = shPe[0][tid] * __expf(mA - m) + shPe[1][tid] * __expf(mB - m);
            const long long pidx = ((long long)blockIdx.z * 16 + blockIdx.y) * 2048 + tileN + tid;
            pPart[pidx] = m;
            pPart[pidx + 16 * 16 * 2048] = e;
        }
    }
}

// ---------------------------------------------------------------------------
// Fused scores+softmax+PV.  Grid (16 q-tiles, 16 heads), block 256 (4 waves).
// Per block: q rows [qt*128,+128), head h.  qh tile staged once (32KB LDS);
// loop 64 key-tiles of 32: S^T = kh_tile @ qh^T (MFMA, D: row=key, col=q),
// normalize p = exp(s - Mg[key]) * iLg[key], write normalized attn (float4),
// pack p -> bf16 LDS (dbuf), PV: O += P @ vhT_tile^T.  1 barrier per tile.
// LDS: qh 32K + kh 2x8K + vh 2x8K + p16 2x8K = 80KB -> 2 blocks/CU.
// All staged tiles use pre-swizzled global source + XOR'd reads (rule 21):
//   256B rows (qh/kh): slot(16B) ^= row&7;  64B rows (vh): slot ^= row&3.
// ---------------------------------------------------------------------------
__global__ __launch_bounds__(256, 2)
void fused_pv(const unsigned short* __restrict__ qh,
              const unsigned short* __restrict__ kh,
              const unsigned short* __restrict__ vhT,
              const float* __restrict__ Mg, const float* __restrict__ iLg,
              float* __restrict__ attn, unsigned short* __restrict__ O)
{
    __shared__ unsigned short qh_s[128 * 128];
    __shared__ unsigned short kh_s[2][32 * 128];
    __shared__ unsigned short vh_s[2][128 * 32];
    __shared__ unsigned short p16[2][128 * 32];

    const int tid = threadIdx.x;
    const int wave = tid >> 6, lane = tid & 63, quad = lane >> 4, l16 = lane & 15;
    const int qt = blockIdx.x, h = blockIdx.y;
    const int wA = wave >> 1, wB = wave & 1;   // S: wA=key-half(16), wB=q-half(64)
                                               // PV: wA=q-half(64),  wB=vd-half(64)
    const unsigned short* qg = qh + (long long)h * 262144 + (long long)qt * 128 * 128;
    const unsigned short* kg = kh + (long long)h * 262144;
    const unsigned short* vg = vhT + (long long)h * 262144;
    const float* mgp = Mg + h * 2048;
    const float* ilp = iLg + h * 2048;
    float* ap = attn + (long long)h * L * L + (long long)qt * 128 * 2048;

    auto stage_kv = [&](int kt, int buf) {
        #pragma unroll
        for (int jj = 0; jj < 2; ++jj) {       // kh tile: 32 rows x 128 dk
            const int c = tid + jj * 256;
            const int rl = c >> 4, sl = (c & 15) ^ (rl & 7);
            gload_lds16(kg + (long long)(kt * 32 + rl) * 128 + sl * 8, &kh_s[buf][c * 8]);
        }
        #pragma unroll
        for (int jj = 0; jj < 2; ++jj) {       // vh tile: 128 vd x 32 keys
            const int c = tid + jj * 256;
            const int vd = c >> 2, sl = (c & 3) ^ (vd & 3);
            gload_lds16(vg + (long long)vd * 2048 + kt * 32 + sl * 8, &vh_s[buf][c * 8]);
        }
    };

    // prologue: qh (8 chunks/thread) + tile 0
    #pragma unroll
    for (int jj = 0; jj < 8; ++jj) {
        const int c = tid + jj * 256;
        const int rl = c >> 4, sl = (c & 15) ^ (rl & 7);
        gload_lds16(qg + (long long)rl * 128 + sl * 8, &qh_s[c * 8]);
    }
    stage_kv(0, 0);
    __syncthreads();

    f32x4 acc_o[4][4] = {};
    const int krow = wA * 16 + l16;            // S A-operand row (key, local)

    for (int t = 0; t < 64; ++t) {
        const int cb = t & 1;
        if (t > 0) {                           // PV(t-1) from dbuf'd p16/vh
            const int pb = cb ^ 1;
            bf16x8 pa[4], vb[4];
            #pragma unroll
            for (int i = 0; i < 4; ++i) {
                const int q = wA * 64 + i * 16 + l16;
                pa[i] = *(const bf16x8*)(&p16[pb][q * 32 + ((quad * 8) ^ ((q & 3) << 3))]);
            }
            #pragma unroll
            for (int j = 0; j < 4; ++j) {
                const int vd = wB * 64 + j * 16 + l16;
                vb[j] = *(const bf16x8*)(&vh_s[pb][vd * 32 + ((quad * 8) ^ ((vd & 3) << 3))]);
            }
            #pragma unroll
            for (int i = 0; i < 4; ++i)
                #pragma unroll
                for (int j = 0; j < 4; ++j)
                    acc_o[i][j] = __builtin_amdgcn_mfma_f32_16x16x32_bf16(pa[i], vb[j], acc_o[i][j], 0, 0, 0);
        }
        __builtin_amdgcn_sched_barrier(0);     // keep PV reads before next stage
        if (t < 63) stage_kv(t + 1, cb ^ 1);

        // S^T(t): 16 MFMA.  A=kh (M=key), B=qh (N=q).
        bf16x8 af[4];
        #pragma unroll
        for (int g = 0; g < 4; ++g)
            af[g] = *(const bf16x8*)(&kh_s[cb][krow * 128 + ((g * 32 + quad * 8) ^ ((krow & 7) << 3))]);
        f32x4 acc_s[4];
        #pragma unroll
        for (int j = 0; j < 4; ++j) {
            const int q = wB * 64 + j * 16 + l16;
            f32x4 s = {};
            #pragma unroll
            for (int g = 0; g < 4; ++g) {
                bf16x8 bq = *(const bf16x8*)(&qh_s[q * 128 + ((g * 32 + quad * 8) ^ ((q & 7) << 3))]);
                s = __builtin_amdgcn_mfma_f32_16x16x32_bf16(af[g], bq, s, 0, 0, 0);
            }
            acc_s[j] = s;
        }

        // normalize + attn write + p16 pack.  D: row(key)=quad*4+r, col(q)=l16.
        const int kb = t * 32 + wA * 16 + quad * 4;
        const f32x4 mg4 = *(const f32x4*)(mgp + kb);
        const f32x4 il4 = *(const f32x4*)(ilp + kb);
        #pragma unroll
        for (int j = 0; j < 4; ++j) {
            const int q = wB * 64 + j * 16 + l16;
            f32x4 p;
            #pragma unroll
            for (int r = 0; r < 4; ++r)
                p[r] = __expf(acc_s[j][r] - mg4[r]) * il4[r];
            *(f32x4*)(ap + (long long)q * 2048 + kb) = p;
            s16x4 pk;
            #pragma unroll
            for (int r = 0; r < 4; ++r) pk[r] = (short)f2bf(p[r]);
            *(s16x4*)(&p16[cb][q * 32 + ((wA * 16 + quad * 4) ^ ((q & 3) << 3))]) = pk;
        }
        __syncthreads();                       // p16(t) visible; stage(t+1) drained
    }

    { // final PV (tile 63, buffers 1)
        bf16x8 pa[4], vb[4];
        #pragma unroll
        for (int i = 0; i < 4; ++i) {
            const int q = wA * 64 + i * 16 + l16;
            pa[i] = *(const bf16x8*)(&p16[1][q * 32 + ((quad * 8) ^ ((q & 3) << 3))]);
        }
        #pragma unroll
        for (int j = 0; j < 4; ++j) {
            const int vd = wB * 64 + j * 16 + l16;
            vb[j] = *(const bf16x8*)(&vh_s[1][vd * 32 + ((quad * 8) ^ ((vd & 3) << 3))]);
        }
        #pragma unroll
        for (int i = 0; i < 4; ++i)
            #pragma unroll
            for (int j = 0; j < 4; ++j)
                acc_o[i][j] = __builtin_amdgcn_mfma_f32_16x16x32_bf16(pa[i], vb[j], acc_o[i][j], 0, 0, 0);
    }

    // O epilogue: O[q][h*128+vd] bf16.  D: row(q)=quad*4+r, col(vd)=l16.
    #pragma unroll
    for (int i = 0; i < 4; ++i) {
        const int q = qt * 128 + wA * 64 + i * 16 + quad * 4;
        #pragma unroll
        for (int j = 0; j < 4; ++j) {
            const int vd = h * 128 + wB * 64 + j * 16 + l16;
            #pragma unroll
            for (int r = 0; r < 4; ++r)
                O[(long long)(q + r) * 2048 + vd] = f2bf(acc_o[i][j][r]);
        }
    }
}

// ---------------------------------------------------------------------------
// Combine the 16 per-row-block (max, expsum) partials into per-(head, key)
// global max and 1/sum.  Grid (2048/256, NH).
// ---------------------------------------------------------------------------
__global__ __launch_bounds__(256)
void colstats(const float* __restrict__ pPart, float* __restrict__ Mg,
              float* __restrict__ iLg)
{
    const int c = blockIdx.x * 256 + threadIdx.x;
    const int h = blockIdx.y;
    const float* pm = pPart + (long long)h * 16 * 2048 + c;
    const float* pe = pm + 16 * 16 * 2048;
    float M = -1e30f;
    #pragma unroll
    for (int b = 0; b < 16; ++b) M = fmaxf(M, pm[b * 2048]);
    float Ls = 0.f;
    #pragma unroll
    for (int b = 0; b < 16; ++b) Ls += pe[b * 2048] * __expf(pm[b * 2048] - M);
    Mg[h * 2048 + c]  = M;
    iLg[h * 2048 + c] = 1.0f / Ls;
}

// ---------------------------------------------------------------------------
// fp32 -> bf16 elementwise for q,k,v (z selects input).  8 elems/thread.
// ---------------------------------------------------------------------------
__global__ __launch_bounds__(256)
void cvt_f2b3(const float* __restrict__ a, const float* __restrict__ b,
              const float* __restrict__ c, unsigned short* __restrict__ out)
{
    const float* in = blockIdx.z == 0 ? a : blockIdx.z == 1 ? b : c;
    const long long i = ((long long)blockIdx.x * 256 + threadIdx.x) * 8;
    const float4 f0 = *(const float4*)(in + i);
    const float4 f1 = *(const float4*)(in + i + 4);
    union { int4 v; unsigned short u[8]; } t;
    t.u[0] = f2bf(f0.x); t.u[1] = f2bf(f0.y); t.u[2] = f2bf(f0.z); t.u[3] = f2bf(f0.w);
    t.u[4] = f2bf(f1.x); t.u[5] = f2bf(f1.y); t.u[6] = f2bf(f1.z); t.u[7] = f2bf(f1.w);
    *(int4*)(out + (long long)blockIdx.z * 4194304 + i) = t.v;
}

// ---------------------------------------------------------------------------
// 32x32 tile transpose, fp32 in -> bf16 out. Block (32,8).
// ---------------------------------------------------------------------------
__global__ __launch_bounds__(256)
void transpose_f2b(const float* __restrict__ in, unsigned short* __restrict__ out,
                   int rows, int cols)
{
    __shared__ float t[32][33];
    const long long base = (long long)blockIdx.z * rows * cols;
    const int c0 = blockIdx.x * 32, r0 = blockIdx.y * 32;
    const int tx = threadIdx.x, ty0 = threadIdx.y;
    #pragma unroll
    for (int jj = 0; jj < 4; ++jj) {
        const int j = ty0 + jj * 8;
        t[j][tx] = in[base + (long long)(r0 + j) * cols + (c0 + tx)];
    }
    __syncthreads();
    #pragma unroll
    for (int jj = 0; jj < 4; ++jj) {
        const int j = ty0 + jj * 8;
        out[base + (long long)(c0 + j) * rows + (r0 + tx)] = f2bf(t[tx][j]);
    }
}

// Fused Wq/Wk/Wv transpose: z in [0,48), widx=z>>4 picks the weight, h=z&15.
__global__ __launch_bounds__(256)
void transpose_f2b3(const float* __restrict__ Wq, const float* __restrict__ Wk,
                    const float* __restrict__ Wv, unsigned short* __restrict__ out)
{
    __shared__ float t[32][33];
    const int z = blockIdx.z, widx = z >> 4, h = z & 15;
    const float* in = (widx == 0 ? Wq : widx == 1 ? Wk : Wv) + (long long)h * 2048 * 128;
    unsigned short* o = out + (long long)z * 262144;
    const int c0 = blockIdx.x * 32, r0 = blockIdx.y * 32;
    const int tx = threadIdx.x, ty0 = threadIdx.y;
    #pragma unroll
    for (int jj = 0; jj < 4; ++jj) {
        const int j = ty0 + jj * 8;
        t[j][tx] = in[(long long)(r0 + j) * 128 + (c0 + tx)];
    }
    __syncthreads();
    #pragma unroll
    for (int jj = 0; jj < 4; ++jj) {
        const int j = ty0 + jj * 8;
        o[(long long)(c0 + j) * 2048 + (r0 + tx)] = f2bf(t[tx][j]);
    }
}

// ---------------------------------------------------------------------------
// Residual + bias + LayerNorm (all fp32), one block (256 thr) per row of 2048.
// ---------------------------------------------------------------------------
__global__ __launch_bounds__(256)
void ln_resid(const float* __restrict__ ypre, const float* __restrict__ resid,
              const float* __restrict__ pb, const float* __restrict__ g,
              const float* __restrict__ bta, float* __restrict__ y)
{
    __shared__ float as_[4], as2_[4];
    const int l = blockIdx.x;
    const int tid = threadIdx.x;
    float v[8]; float s = 0.f, s2 = 0.f;
    #pragma unroll
    for (int i = 0; i < 8; ++i) {
        const int d = tid + i * 256;
        float t = ypre[(long long)l * DMODEL + d] + pb[d] + resid[(long long)l * DMODEL + d];
        v[i] = t; s += t; s2 += t * t;
    }
    #pragma unroll
    for (int off = 32; off > 0; off >>= 1) {
        s  += __shfl_down(s, off, 64);
        s2 += __shfl_down(s2, off, 64);
    }
    const int wave = tid >> 6, lane = tid & 63;
    if (lane == 0) { as_[wave] = s; as2_[wave] = s2; }
    __syncthreads();
    const float S  = as_[0] + as_[1] + as_[2] + as_[3];
    const float S2 = as2_[0] + as2_[1] + as2_[2] + as2_[3];
    const float mu  = S * (1.0f / DMODEL);
    const float var = S2 * (1.0f / DMODEL) - mu * mu;
    const float rs  = rsqrtf(var + 1e-5f);
    #pragma unroll
    for (int i = 0; i < 8; ++i) {
        const int d = tid + i * 256;
        y[(long long)l * DMODEL + d] = (v[i] - mu) * rs * g[d] + bta[d];
    }
}

// ---------------------------------------------------------------------------
extern "C" void kernel_launch(void* const* d_in, const int* in_sizes, int n_in,
                              void* d_out, int out_size, void* d_ws, size_t ws_size,
                              hipStream_t stream)
{
    const float* q  = (const float*)d_in[0];
    const float* k  = (const float*)d_in[1];
    const float* v  = (const float*)d_in[2];
    const float* Wq = (const float*)d_in[3];
    const float* Wk = (const float*)d_in[4];
    const float* Wv = (const float*)d_in[5];
    const float* Pw = (const float*)d_in[6];
    const float* Pb = (const float*)d_in[7];
    const float* Lg = (const float*)d_in[8];
    const float* Lb = (const float*)d_in[9];

    float* y    = (float*)d_out;
    float* attn = y + (size_t)L * DMODEL;               // output 1 (fp32), 268 MB

    // ws layout (bf16 elems), 40 MB:
    //   T0 [0,8MB): softmax stats (pPart 4MB + Mg/iLg) during attention,
    //               then Pw^T (8MB) for the proj GEMM (strictly after fused).
    //   qh [8,16), kh [16,24), vhT [24,32), O [32,40)
    //   ypre fp32 overlays qh+kh (dead after fused).
    // attn output region (268MB) is dead until fused writes it, so bf16
    // q,k,v (24MB) + Wq/Wk/Wv^T (24MB) are stashed there first.
    const size_t SEG = (size_t)4194304;
    unsigned short* T0  = (unsigned short*)d_ws;
    unsigned short* qh  = T0 + SEG;
    unsigned short* kh  = qh + SEG;
    unsigned short* vhT = kh + SEG;
    unsigned short* O   = vhT + SEG;
    float* ypre  = (float*)qh;
    float* pPart = (float*)d_ws;                        // [2][16][16][2048] fp32 = 4MB
    float* Mg    = pPart + 2 * 16 * 16 * 2048;          // [16][2048]
    float* iLg   = Mg + 16 * 2048;

    unsigned short* qkvb = (unsigned short*)attn;       // qb,kb,vb: 3 x SEG
    unsigned short* WT   = qkvb + 3 * SEG;              // WqT,WkT,WvT: 48 x 262144

    const float inv_temper = 0.022097086912079608f;     // 1/sqrt(2048)
    dim3 tb(32, 8);

    // Stage 0: bf16-ify q,k,v; transpose all three weights.
    cvt_f2b3<<<dim3(2048, 1, 3), 256, 0, stream>>>(q, k, v, qkvb);
    transpose_f2b3<<<dim3(4, 64, 48), tb, 0, stream>>>(Wq, Wk, Wv, WT);

    // Stage 1: fused Q/K/V projections, z = 48 (3 x 16 heads).
    gemm_bt<3, 128, 32, 0><<<dim3(1, 16, 48), 256, 0, stream>>>(qkvb, WT, qh,
        2048, 2048, 2048, 0, 4194304LL, 262144LL, 262144LL, inv_temper, nullptr);

    // Stage 2: stats pass — S = qh @ kh^T computed tile-wise, NO logits write,
    // only per-block column (max, expsum) partials.
    gemm_bt<4, 128, 32, 1><<<dim3(16, 16, 16), 256, 0, stream>>>(qh, kh, nullptr,
        128, 128, 128, 0, 262144LL, 262144LL, 0LL, 1.0f, pPart);

    // Stage 3: reduce partials -> per-(head,key) global max & 1/sum.
    colstats<<<dim3(8, NH), 256, 0, stream>>>(pPart, Mg, iLg);

    // Stage 4: fused recompute-S + normalize + attn write + PV.
    fused_pv<<<dim3(16, NH), 256, 0, stream>>>(qh, kh, vhT, Mg, iLg, attn, O);

    // Stage 5: ypre = O @ proj_w  (fp32 out, M=N=K=2048), BK=64.
    transpose_f2b<<<dim3(64, 64, 1), tb, 0, stream>>>(Pw, T0, 2048, 2048);
    gemm_bt<2, 64, 64, 0><<<dim3(16, 32, 1), 256, 0, stream>>>(O, T0, (void*)ypre,
        2048, 2048, 2048, 2048, 0LL, 0LL, 0LL, 1.0f, nullptr);

    // Stage 6: y = LayerNorm(ypre + proj_b + residual) * g + b
    ln_resid<<<dim3(2048), 256, 0, stream>>>(ypre, q, Pb, Lg, Lb, y);
}